// Round 16
// baseline (1372.343 us; speedup 1.0000x reference)
//
#include <hip/hip_runtime.h>
#include <hip/hip_fp16.h>

#define NN 40000
#define DD 64
#define EE 800000
#define NHOP 5
#define NSEM 128
#define NBK 625          // NN/64 buckets for binned scatter
#define BINCH 8192       // edges per binA/binCount block

__device__ __forceinline__ float leaky02(float v) { return v > 0.f ? v : 0.2f * v; }
__device__ __forceinline__ float tanh_fast(float x) {
  return 1.f - 2.f / (__expf(2.f * x) + 1.f);
}
__device__ __forceinline__ float wred(float x) {
  #pragma unroll
  for (int m = 1; m < 64; m <<= 1) x += __shfl_xor(x, m);
  return x;
}

// ---------------- zero kernel ----------------
__global__ void zero_i32(int* __restrict__ p, int n) {
  int i = blockIdx.x * blockDim.x + threadIdx.x;
  if (i < n) p[i] = 0;
}

// ---------------- projection GEMM: 32x64 tile, BK=32, 128 thr, 4x4 acc ----------------
#define PBK 32
__global__ __launch_bounds__(128) void proj_gemm_relu2(
    const float* __restrict__ Xa, const float* __restrict__ Wa,
    const float* __restrict__ ba, float* __restrict__ oa, __half* __restrict__ oa16,
    const float* __restrict__ Xp, const float* __restrict__ Wp,
    const float* __restrict__ bp, float* __restrict__ op, __half* __restrict__ op16)
{
  int side = blockIdx.y;
  const float* X = side ? Xp : Xa;
  const float* W = side ? Wp : Wa;
  const float* bias = side ? bp : ba;
  float* out = side ? op : oa;
  __half* out16 = side ? op16 : oa16;
  int K = side ? 512 : 334;

  __shared__ float As[32][PBK + 1];
  __shared__ float Bs[PBK][DD];
  int tid = threadIdx.x;
  int tx = tid & 15;       // col quad (4 cols)
  int ty = tid >> 4;       // row quad (4 rows), 0..7
  int row0 = blockIdx.x * 32;
  float acc[4][4] = {{0.f}};
  int nk = (K + PBK - 1) / PBK;
  for (int kt = 0; kt < nk; ++kt) {
    int k0 = kt * PBK;
    #pragma unroll
    for (int j = 0; j < 8; ++j) {
      int idx = tid + j * 128;
      int r = idx >> 5, c = idx & 31;
      int gk = k0 + c;
      As[r][c] = (gk < K) ? X[(size_t)(row0 + r) * K + gk] : 0.f;
    }
    #pragma unroll
    for (int j = 0; j < 4; ++j) {
      int idx = tid + j * 128;
      int r = idx >> 4, c4 = idx & 15;
      int gk = k0 + r;
      float4 v = (gk < K) ? ((const float4*)(W + (size_t)gk * DD))[c4]
                          : make_float4(0.f, 0.f, 0.f, 0.f);
      ((float4*)&Bs[r][0])[c4] = v;
    }
    __syncthreads();
    #pragma unroll 8
    for (int kk = 0; kk < PBK; ++kk) {
      float a0 = As[ty * 4 + 0][kk];
      float a1 = As[ty * 4 + 1][kk];
      float a2 = As[ty * 4 + 2][kk];
      float a3 = As[ty * 4 + 3][kk];
      float4 bv = ((float4*)&Bs[kk][0])[tx];
      acc[0][0] = fmaf(a0, bv.x, acc[0][0]);
      acc[0][1] = fmaf(a0, bv.y, acc[0][1]);
      acc[0][2] = fmaf(a0, bv.z, acc[0][2]);
      acc[0][3] = fmaf(a0, bv.w, acc[0][3]);
      acc[1][0] = fmaf(a1, bv.x, acc[1][0]);
      acc[1][1] = fmaf(a1, bv.y, acc[1][1]);
      acc[1][2] = fmaf(a1, bv.z, acc[1][2]);
      acc[1][3] = fmaf(a1, bv.w, acc[1][3]);
      acc[2][0] = fmaf(a2, bv.x, acc[2][0]);
      acc[2][1] = fmaf(a2, bv.y, acc[2][1]);
      acc[2][2] = fmaf(a2, bv.z, acc[2][2]);
      acc[2][3] = fmaf(a2, bv.w, acc[2][3]);
      acc[3][0] = fmaf(a3, bv.x, acc[3][0]);
      acc[3][1] = fmaf(a3, bv.y, acc[3][1]);
      acc[3][2] = fmaf(a3, bv.z, acc[3][2]);
      acc[3][3] = fmaf(a3, bv.w, acc[3][3]);
    }
    __syncthreads();
  }
  float4 bb = ((const float4*)bias)[tx];
  #pragma unroll
  for (int i = 0; i < 4; ++i) {
    int gr = row0 + ty * 4 + i;
    float4 v;
    v.x = fmaxf(acc[i][0] + bb.x, 0.f);
    v.y = fmaxf(acc[i][1] + bb.y, 0.f);
    v.z = fmaxf(acc[i][2] + bb.z, 0.f);
    v.w = fmaxf(acc[i][3] + bb.w, 0.f);
    ((float4*)(out + (size_t)gr * DD))[tx] = v;
    __half2 p0 = __floats2half2_rn(v.x, v.y);
    __half2 p1 = __floats2half2_rn(v.z, v.w);
    ((__half2*)(out16 + (size_t)gr * DD))[tx * 2 + 0] = p0;
    ((__half2*)(out16 + (size_t)gr * DD))[tx * 2 + 1] = p1;
  }
}

// ---------------- CSR build: bucket counts (LDS-privatized) ----------------
__global__ __launch_bounds__(256) void binCount_kernel(
    const int* __restrict__ e0, const int* __restrict__ e1,
    const int* __restrict__ e2, const int* __restrict__ e3,
    int* __restrict__ bcnt, int e)
{
  int rel = blockIdx.y;
  const int* S = rel == 0 ? e0 : rel == 1 ? e1 : rel == 2 ? e2 : e3;
  __shared__ int cnt[NBK];
  int tid = threadIdx.x;
  for (int b = tid; b < NBK; b += 256) cnt[b] = 0;
  __syncthreads();
  int e0i = blockIdx.x * BINCH;
  int ne = min(BINCH, e - e0i);
  for (int i = tid; i < ne; i += 256) atomicAdd(&cnt[S[e0i + i] >> 6], 1);
  __syncthreads();
  for (int b = tid; b < NBK; b += 256)
    if (cnt[b]) atomicAdd(&bcnt[rel * NBK + b], cnt[b]);
}

// bucket scan -> bucket bases + cursor seed; also sets rowptr[NN]=E
__global__ __launch_bounds__(1024) void bucketScan_kernel(
    const int* __restrict__ bcnt, int* __restrict__ bbase, int* __restrict__ bcur,
    int* __restrict__ rp0, int* __restrict__ rp1, int* __restrict__ rp2,
    int* __restrict__ rp3, int e)
{
  int rel = blockIdx.x;
  __shared__ int sh[1024];
  int t = threadIdx.x;
  int v = (t < NBK) ? bcnt[rel * NBK + t] : 0;
  sh[t] = v;
  __syncthreads();
  for (int off = 1; off < 1024; off <<= 1) {
    int y = (t >= off) ? sh[t - off] : 0;
    __syncthreads();
    sh[t] += y;
    __syncthreads();
  }
  if (t < NBK) {
    int base = sh[t] - v;
    bbase[rel * (NBK + 1) + t] = base;
    bcur[rel * NBK + t] = base;
  }
  if (t == 0) {
    bbase[rel * (NBK + 1) + NBK] = e;
    (rel == 0 ? rp0 : rel == 1 ? rp1 : rel == 2 ? rp2 : rp3)[NN] = e;
  }
}

// pass A: bin edges into buckets, packed u32 = (s&63)<<16 | t
__global__ __launch_bounds__(256) void binA_kernel(
    const int* __restrict__ e0, const int* __restrict__ e1,
    const int* __restrict__ e2, const int* __restrict__ e3,
    int* __restrict__ bcur, unsigned* __restrict__ pairbuf, int e)
{
  int rel = blockIdx.y;
  const int* S = rel == 0 ? e0 : rel == 1 ? e1 : rel == 2 ? e2 : e3;
  const int* T = S + e;
  unsigned* pb = pairbuf + (size_t)rel * e;
  __shared__ int cnt[NBK], base[NBK], cnt2[NBK];
  int tid = threadIdx.x;
  for (int b = tid; b < NBK; b += 256) { cnt[b] = 0; cnt2[b] = 0; }
  __syncthreads();
  int e0i = blockIdx.x * BINCH;
  int ne = min(BINCH, e - e0i);
  for (int i = tid; i < ne; i += 256) atomicAdd(&cnt[S[e0i + i] >> 6], 1);
  __syncthreads();
  for (int b = tid; b < NBK; b += 256)
    base[b] = cnt[b] ? atomicAdd(&bcur[rel * NBK + b], cnt[b]) : 0;
  __syncthreads();
  for (int i = tid; i < ne; i += 256) {
    int s = S[e0i + i];
    int t = T[e0i + i];
    int b = s >> 6;
    int off = atomicAdd(&cnt2[b], 1);
    pb[base[b] + off] = ((unsigned)(s & 63) << 16) | (unsigned)t;
  }
}

// pass B: per bucket — local per-node counts, wave prefix -> rowptr, place targets (u16)
__global__ __launch_bounds__(256) void binB_kernel(
    const unsigned* __restrict__ pairbuf, const int* __restrict__ bbase,
    int* __restrict__ rp0, int* __restrict__ rp1, int* __restrict__ rp2,
    int* __restrict__ rp3,
    unsigned short* __restrict__ ts0, unsigned short* __restrict__ ts1,
    unsigned short* __restrict__ ts2, unsigned short* __restrict__ ts3, int e)
{
  int rel = blockIdx.y;
  int* rowptr = rel == 0 ? rp0 : rel == 1 ? rp1 : rel == 2 ? rp2 : rp3;
  unsigned short* ts = rel == 0 ? ts0 : rel == 1 ? ts1 : rel == 2 ? ts2 : ts3;
  const unsigned* pb = pairbuf + (size_t)rel * e;
  int b = blockIdx.x;
  int bstart = bbase[rel * (NBK + 1) + b];
  int bend   = bbase[rel * (NBK + 1) + b + 1];
  __shared__ int ncnt[64], cur[64];
  int tid = threadIdx.x;
  if (tid < 64) ncnt[tid] = 0;
  __syncthreads();
  for (int i = bstart + tid; i < bend; i += 256)
    atomicAdd(&ncnt[(pb[i] >> 16) & 63], 1);
  __syncthreads();
  if (tid < 64) {                       // wave 0: 64-wide inclusive scan
    int v = ncnt[tid];
    int x = v;
    #pragma unroll
    for (int off = 1; off < 64; off <<= 1) {
      int y = __shfl_up(x, off);
      if (tid >= off) x += y;
    }
    int nb = bstart + x - v;            // exclusive prefix
    rowptr[b * 64 + tid] = nb;
    cur[tid] = nb;
  }
  __syncthreads();
  for (int i = bstart + tid; i < bend; i += 256) {
    unsigned u = pb[i];
    int pos = atomicAdd(&cur[(u >> 16) & 63], 1);
    ts[pos] = (unsigned short)(u & 0xffffu);
  }
}

// ---------------- upfront x1/w2 (all hops) + hop-0 h1 : thread-per-node ----------------
__global__ __launch_bounds__(256) void precompute_xw(
    const float* __restrict__ xA, const float* __restrict__ xP,
    const float* __restrict__ a1_ap, const float* __restrict__ a2_ap,
    const float* __restrict__ a1_aa, const float* __restrict__ a2_aa,
    const float* __restrict__ a1_pa, const float* __restrict__ a2_pa,
    const float* __restrict__ a1_pp, const float* __restrict__ a2_pp,
    float* __restrict__ x1all, float* __restrict__ w2all,
    float* __restrict__ h1_ap, float* __restrict__ h1_aa,
    float* __restrict__ h1_pa, float* __restrict__ h1_pp)
{
  int side = blockIdx.y;
  __shared__ float L[21 * DD];
  int tid = threadIdx.x;
  {
    const float* s0 = side ? a1_pa : a1_ap;
    const float* s1 = side ? a2_pa : a2_ap;
    const float* s2 = side ? a1_pp : a1_aa;
    const float* s3 = side ? a2_pp : a2_aa;
    const float* ex = side ? a2_ap : a2_pa;   // hop-0 cross-side extra
    for (int i = tid; i < 21 * DD; i += 256) {
      int k = i >> 6, d = i & 63;
      const float* src = (k < 5) ? s0 : (k < 10) ? s1 : (k < 15) ? s2 : (k < 20) ? s3 : ex;
      int hop = (k < 20) ? (k % 5) : 0;
      L[i] = src[hop * DD + d];
    }
  }
  __syncthreads();
  int j = blockIdx.x * 256 + tid;
  if (j >= NN) return;
  const float4* x4 = (const float4*)((side ? xP : xA) + (size_t)j * DD);
  float acc[21];
  #pragma unroll
  for (int k = 0; k < 21; ++k) acc[k] = 0.f;
  #pragma unroll
  for (int d0 = 0; d0 < 16; ++d0) {
    float4 v = x4[d0];
    #pragma unroll
    for (int c = 0; c < 4; ++c) {
      int d = d0 * 4 + c;
      float xv = (&v.x)[c];
      #pragma unroll
      for (int k = 0; k < 21; ++k) acc[k] = fmaf(xv, L[k * DD + d], acc[k]);
    }
  }
  int relA = side ? 2 : 0;
  #pragma unroll
  for (int i = 0; i < NHOP; ++i) {
    x1all[((size_t)(relA + 0) * NHOP + i) * NN + j] = acc[0 * 5 + i];
    w2all[((size_t)(relA + 0) * NHOP + i) * NN + j] =
        __expf(leaky02(acc[0 * 5 + i] + acc[1 * 5 + i]));
    x1all[((size_t)(relA + 1) * NHOP + i) * NN + j] = acc[2 * 5 + i];
    w2all[((size_t)(relA + 1) * NHOP + i) * NN + j] =
        __expf(leaky02(acc[2 * 5 + i] + acc[3 * 5 + i]));
  }
  if (side) { h1_pp[j] = acc[15]; h1_ap[j] = acc[20]; }
  else      { h1_aa[j] = acc[15]; h1_pa[j] = acc[20]; }
}

// ---------------- fused edge aggregation: 8-deep half2 gathers + XCD partition ----------------
struct AggRel {
  const float* x; const __half2* h2; const float* x1; const float* w2; const float* h1;
  const int* rowptr; const unsigned short* tsorted; float* out;
};

__global__ __launch_bounds__(256) void agg4_kernel(AggRel r0, AggRel r1, AggRel r2,
                                                   AggRel r3, int n)
{
  int bid = blockIdx.x;
  int g = (bid >> 2) & 1;
  int u = (bid >> 3) * 4 + (bid & 3);       // 0 .. n/2-1
  int half = n >> 2;                        // blocks per relation (10000)
  int relsel = u >= half;
  int nodeblk = relsel ? (u - half) : u;
  AggRel R;
  if (g == 0) R = relsel ? r2 : r1;
  else        R = relsel ? r3 : r0;

  int wid = nodeblk * 4 + (threadIdx.x >> 6);
  int lane = threadIdx.x & 63;
  int pair = lane >> 5;        // 0: even edges, 1: odd edges
  int c2 = lane & 31;          // half2 column index (cols 2*c2, 2*c2+1)

  int beg = R.rowptr[wid], end = R.rowptr[wid + 1];
  float x1i = R.x1[wid];
  float2 a0v = make_float2(0.f, 0.f), a1v = make_float2(0.f, 0.f);
  float2 a2v = make_float2(0.f, 0.f), a3v = make_float2(0.f, 0.f);
  float2 a4v = make_float2(0.f, 0.f), a5v = make_float2(0.f, 0.f);
  float2 a6v = make_float2(0.f, 0.f), a7v = make_float2(0.f, 0.f);
  float wsumL = 0.f;
  for (int c = beg; c < end; c += 64) {
    int idx = c + lane;
    int t = 0;
    float wv = 0.f;
    if (idx < end) {
      t = R.tsorted[idx];
      wv = __expf(leaky02(x1i + R.h1[t]));
    }
    wsumL += wv;
    int ne = min(64, end - c);
    for (int j = 0; j < ne; j += 16) {     // phantom edges: wv==0, t==0 (safe)
      int s0 = j + pair,      s1 = j + 2 + pair,  s2 = j + 4 + pair,  s3 = j + 6 + pair;
      int s4 = j + 8 + pair,  s5 = j + 10 + pair, s6 = j + 12 + pair, s7 = j + 14 + pair;
      int t0 = __shfl(t, s0), t1 = __shfl(t, s1), t2 = __shfl(t, s2), t3 = __shfl(t, s3);
      int t4 = __shfl(t, s4), t5 = __shfl(t, s5), t6 = __shfl(t, s6), t7 = __shfl(t, s7);
      float w0 = __shfl(wv, s0), w1 = __shfl(wv, s1), w2_ = __shfl(wv, s2), w3 = __shfl(wv, s3);
      float w4 = __shfl(wv, s4), w5 = __shfl(wv, s5), w6 = __shfl(wv, s6), w7 = __shfl(wv, s7);
      float2 f0 = __half22float2(R.h2[((unsigned)t0 << 5) + c2]);
      float2 f1 = __half22float2(R.h2[((unsigned)t1 << 5) + c2]);
      float2 f2 = __half22float2(R.h2[((unsigned)t2 << 5) + c2]);
      float2 f3 = __half22float2(R.h2[((unsigned)t3 << 5) + c2]);
      float2 f4 = __half22float2(R.h2[((unsigned)t4 << 5) + c2]);
      float2 f5 = __half22float2(R.h2[((unsigned)t5 << 5) + c2]);
      float2 f6 = __half22float2(R.h2[((unsigned)t6 << 5) + c2]);
      float2 f7 = __half22float2(R.h2[((unsigned)t7 << 5) + c2]);
      a0v.x = fmaf(w0, f0.x, a0v.x);  a0v.y = fmaf(w0, f0.y, a0v.y);
      a1v.x = fmaf(w1, f1.x, a1v.x);  a1v.y = fmaf(w1, f1.y, a1v.y);
      a2v.x = fmaf(w2_, f2.x, a2v.x); a2v.y = fmaf(w2_, f2.y, a2v.y);
      a3v.x = fmaf(w3, f3.x, a3v.x);  a3v.y = fmaf(w3, f3.y, a3v.y);
      a4v.x = fmaf(w4, f4.x, a4v.x);  a4v.y = fmaf(w4, f4.y, a4v.y);
      a5v.x = fmaf(w5, f5.x, a5v.x);  a5v.y = fmaf(w5, f5.y, a5v.y);
      a6v.x = fmaf(w6, f6.x, a6v.x);  a6v.y = fmaf(w6, f6.y, a6v.y);
      a7v.x = fmaf(w7, f7.x, a7v.x);  a7v.y = fmaf(w7, f7.y, a7v.y);
    }
  }
  float wsum = wred(wsumL);
  float2 acc;
  acc.x = ((a0v.x + a1v.x) + (a2v.x + a3v.x)) + ((a4v.x + a5v.x) + (a6v.x + a7v.x));
  acc.y = ((a0v.y + a1v.y) + (a2v.y + a3v.y)) + ((a4v.y + a5v.y) + (a6v.y + a7v.y));
  acc.x += __shfl_xor(acc.x, 32);            // fold odd-edge half into even half
  acc.y += __shfl_xor(acc.y, 32);
  if (pair == 0) {
    float w2v = R.w2[wid];
    float inv = 1.f / (wsum + w2v);
    float2 xv = ((const float2*)(R.x + (size_t)wid * DD))[c2];
    float2 o;
    o.x = fmaf(w2v, xv.x, acc.x) * inv;
    o.y = fmaf(w2v, xv.y, acc.y) * inv;
    ((float2*)(R.out + (size_t)wid * DD))[c2] = o;
  }
}

// ---------------- semantic attention + fused beta (last-block reduction) ----------------
__global__ __launch_bounds__(256) void sem_kernel(
    const float* __restrict__ eA0, const float* __restrict__ eA1,
    const float* __restrict__ eP0, const float* __restrict__ eP1,
    const float* __restrict__ Wa, const float* __restrict__ ba, const float* __restrict__ qa,
    const float* __restrict__ Wp, const float* __restrict__ bp, const float* __restrict__ qp,
    float* __restrict__ psums, float* __restrict__ beta, int* __restrict__ ctr)
{
  int side = blockIdx.y;
  const float* e0 = side ? eP0 : eA0;
  const float* e1 = side ? eP1 : eA1;
  const float* W = side ? Wp : Wa;
  const float* b = side ? bp : ba;
  const float* q = side ? qp : qa;

  __shared__ float Ws[DD * NSEM];
  __shared__ float zt[2][DD][12];        // 8 nodes transposed (+4 pad, float4-aligned)
  __shared__ float red0[256], red1[256];
  int tid = threadIdx.x;
  {
    const float4* W4 = (const float4*)W;
    float4* Ws4 = (float4*)Ws;
    #pragma unroll
    for (int j = 0; j < 8; ++j) Ws4[tid + j * 256] = W4[tid + j * 256];
  }
  int slot = tid >> 7;                   // 2 slots x 4 nodes
  int k = tid & 127;
  float bk = b[k], qk = q[k];
  int base = blockIdx.x * 64;
  float sum0 = 0.f, sum1 = 0.f;
  for (int it = 0; it < 8; ++it) {
    #pragma unroll
    for (int j = 0; j < 4; ++j) {
      int idx = tid + j * 256;
      int d = idx & 63, m = (idx >> 6) & 1, nn = idx >> 7;
      zt[m][d][nn] = (m ? e1 : e0)[(size_t)(base + it * 8 + nn) * DD + d];
    }
    __syncthreads();
    float a0[4], a1[4];
    #pragma unroll
    for (int nn = 0; nn < 4; ++nn) { a0[nn] = bk; a1[nn] = bk; }
    #pragma unroll 8
    for (int d = 0; d < DD; ++d) {
      float w = Ws[d * NSEM + k];
      float4 za = *(const float4*)&zt[0][d][slot * 4];
      float4 zb = *(const float4*)&zt[1][d][slot * 4];
      a0[0] = fmaf(za.x, w, a0[0]);
      a0[1] = fmaf(za.y, w, a0[1]);
      a0[2] = fmaf(za.z, w, a0[2]);
      a0[3] = fmaf(za.w, w, a0[3]);
      a1[0] = fmaf(zb.x, w, a1[0]);
      a1[1] = fmaf(zb.y, w, a1[1]);
      a1[2] = fmaf(zb.z, w, a1[2]);
      a1[3] = fmaf(zb.w, w, a1[3]);
    }
    #pragma unroll
    for (int nn = 0; nn < 4; ++nn) {
      sum0 += tanh_fast(a0[nn]) * qk;
      sum1 += tanh_fast(a1[nn]) * qk;
    }
    __syncthreads();
  }
  red0[tid] = sum0;
  red1[tid] = sum1;
  __syncthreads();
  for (int off = 128; off; off >>= 1) {
    if (tid < off) { red0[tid] += red0[tid + off]; red1[tid] += red1[tid + off]; }
    __syncthreads();
  }
  if (tid == 0) {
    int idx = (side * gridDim.x + blockIdx.x) * 2;
    psums[idx + 0] = red0[0];
    psums[idx + 1] = red1[0];
  }
  // ---- fused beta: last arriving block reduces all psums (deterministic) ----
  __threadfence();
  __shared__ int lastFlag;
  if (tid == 0)
    lastFlag = (atomicAdd(ctr, 1) == (int)(2 * gridDim.x) - 1);
  __syncthreads();
  if (!lastFlag) return;
  __threadfence();
  int nblk = gridDim.x;
  float a0 = 0.f, a1 = 0.f, p0 = 0.f, p1 = 0.f;
  for (int i = tid; i < nblk; i += 256) {
    a0 += psums[i * 2];
    a1 += psums[i * 2 + 1];
    p0 += psums[(nblk + i) * 2];
    p1 += psums[(nblk + i) * 2 + 1];
  }
  float* red2 = &zt[0][0][0];
  float* red3 = red2 + 256;
  red0[tid] = a0; red1[tid] = a1; red2[tid] = p0; red3[tid] = p1;
  __syncthreads();
  for (int off = 128; off; off >>= 1) {
    if (tid < off) {
      red0[tid] += red0[tid + off]; red1[tid] += red1[tid + off];
      red2[tid] += red2[tid + off]; red3[tid] += red3[tid + off];
    }
    __syncthreads();
  }
  if (tid == 0) {
    float invn = 1.f / NN;
    float m0 = red0[0] * invn, m1 = red1[0] * invn;
    float mx = fmaxf(m0, m1);
    float x0 = __expf(m0 - mx), x1 = __expf(m1 - mx);
    float inv = 1.f / (x0 + x1);
    beta[0] = x0 * inv; beta[1] = x1 * inv;
    m0 = red2[0] * invn; m1 = red3[0] * invn;
    mx = fmaxf(m0, m1);
    x0 = __expf(m0 - mx); x1 = __expf(m1 - mx);
    inv = 1.f / (x0 + x1);
    beta[2] = x0 * inv; beta[3] = x1 * inv;
    *ctr = 0;                           // reset for next hop
  }
}

// ---------------- combine + ELU + fp16 copy + fused next-hop h1 (shfl 16-lane dots) ----------------
__global__ void combine2_kernel(const float4* __restrict__ eA0, const float4* __restrict__ eA1,
    const float4* __restrict__ eP0, const float4* __restrict__ eP1,
    const float* __restrict__ beta, float4* __restrict__ hA, float4* __restrict__ hP,
    __half2* __restrict__ hA16, __half2* __restrict__ hP16,
    const float* __restrict__ a2_ap_n, const float* __restrict__ a2_aa_n,
    const float* __restrict__ a2_pa_n, const float* __restrict__ a2_pp_n,
    float* __restrict__ h1_ap, float* __restrict__ h1_aa,
    float* __restrict__ h1_pa, float* __restrict__ h1_pp,
    int has_next, int nvec)
{
  int side = blockIdx.y;
  int i = blockIdx.x * 256 + threadIdx.x;
  if (i >= nvec) return;
  float b0 = beta[side * 2], b1 = beta[side * 2 + 1];
  float4 v0 = (side ? eP0 : eA0)[i];
  float4 v1 = (side ? eP1 : eA1)[i];
  float4 r;
  float t;
  t = b0 * v0.x + b1 * v1.x; r.x = t > 0.f ? t : (__expf(t) - 1.f);
  t = b0 * v0.y + b1 * v1.y; r.y = t > 0.f ? t : (__expf(t) - 1.f);
  t = b0 * v0.z + b1 * v1.z; r.z = t > 0.f ? t : (__expf(t) - 1.f);
  t = b0 * v0.w + b1 * v1.w; r.w = t > 0.f ? t : (__expf(t) - 1.f);
  (side ? hP : hA)[i] = r;
  (side ? hP16 : hA16)[i * 2 + 0] = __floats2half2_rn(r.x, r.y);
  (side ? hP16 : hA16)[i * 2 + 1] = __floats2half2_rn(r.z, r.w);
  if (has_next) {
    // row = i>>4; its 16 float4-threads are consecutive lanes in one wave
    int col4 = i & 15;
    const float* ax = side ? a2_ap_n : a2_aa_n;
    const float* ay = side ? a2_pp_n : a2_pa_n;
    float4 a4 = ((const float4*)ax)[col4];
    float4 c4 = ((const float4*)ay)[col4];
    float rx = r.x * a4.x + r.y * a4.y + r.z * a4.z + r.w * a4.w;
    float ry = r.x * c4.x + r.y * c4.y + r.z * c4.z + r.w * c4.w;
    #pragma unroll
    for (int m = 1; m < 16; m <<= 1) {
      rx += __shfl_xor(rx, m);
      ry += __shfl_xor(ry, m);
    }
    if ((threadIdx.x & 15) == 0) {
      int row = i >> 4;
      if (side) { h1_ap[row] = rx; h1_pp[row] = ry; }
      else      { h1_aa[row] = rx; h1_pa[row] = ry; }
    }
  }
}

// ---------------- final projection ----------------
__global__ void final_kernel(const float* __restrict__ hA, const float* __restrict__ W2,
    const float* __restrict__ b2, float* __restrict__ out, int n)
{
  int j = blockIdx.x * blockDim.x + threadIdx.x;
  if (j >= n) return;
  float acc0 = b2[0], acc1 = b2[1], acc2 = b2[2], acc3 = b2[3];
  const float4* hrow = (const float4*)(hA + (size_t)j * DD);
  #pragma unroll
  for (int d4 = 0; d4 < 16; ++d4) {
    float4 v = hrow[d4];
    #pragma unroll
    for (int c = 0; c < 4; ++c) {
      int d = d4 * 4 + c;
      float vv = (&v.x)[c];
      acc0 = fmaf(vv, W2[d * 4 + 0], acc0);
      acc1 = fmaf(vv, W2[d * 4 + 1], acc1);
      acc2 = fmaf(vv, W2[d * 4 + 2], acc2);
      acc3 = fmaf(vv, W2[d * 4 + 3], acc3);
    }
  }
  ((float4*)out)[j] = make_float4(acc0, acc1, acc2, acc3);
}

extern "C" void kernel_launch(void* const* d_in, const int* in_sizes, int n_in,
                              void* d_out, int out_size, void* d_ws, size_t ws_size,
                              hipStream_t stream)
{
  const float* x_author = (const float*)d_in[0];
  const float* x_paper  = (const float*)d_in[1];
  const float* W1_a = (const float*)d_in[2];
  const float* b1_a = (const float*)d_in[3];
  const float* W1_p = (const float*)d_in[4];
  const float* b1_p = (const float*)d_in[5];
  const float* a1_ap = (const float*)d_in[6];
  const float* a2_ap = (const float*)d_in[7];
  const float* a1_aa = (const float*)d_in[8];
  const float* a2_aa = (const float*)d_in[9];
  const float* a1_pa = (const float*)d_in[10];
  const float* a2_pa = (const float*)d_in[11];
  const float* a1_pp = (const float*)d_in[12];
  const float* a2_pp = (const float*)d_in[13];
  const float* semW_a = (const float*)d_in[14];
  const float* semb_a = (const float*)d_in[15];
  const float* semq_a = (const float*)d_in[16];
  const float* semW_p = (const float*)d_in[17];
  const float* semb_p = (const float*)d_in[18];
  const float* semq_p = (const float*)d_in[19];
  const float* W2 = (const float*)d_in[20];
  const float* b2 = (const float*)d_in[21];
  const int* ei[4] = {(const int*)d_in[22], (const int*)d_in[23],
                      (const int*)d_in[24], (const int*)d_in[25]};

  // ---- workspace carve ----
  char* w = (char*)d_ws;
  auto alloc = [&](size_t bytes) -> void* {
    void* p = (void*)w;
    w += (bytes + 255) & ~(size_t)255;
    return p;
  };
  const size_t matB = (size_t)NN * DD * sizeof(float);
  float* xA  = (float*)alloc(matB);
  float* xP  = (float*)alloc(matB);
  float* hA  = (float*)alloc(matB);
  float* hP  = (float*)alloc(matB);
  float* eA0 = (float*)alloc(matB);
  float* eA1 = (float*)alloc(matB);
  float* eP0 = (float*)alloc(matB);
  float* eP1 = (float*)alloc(matB);
  // fp16 gather buffers; hA16 aliases xA16 (proj rewrites each call before use)
  __half* xA16 = (__half*)alloc(matB / 2);
  __half* xP16 = (__half*)alloc(matB / 2);
  __half* hA16 = xA16;
  __half* hP16 = xP16;
  // pairbuf (4*E u32 = 12.8 MB) aliases eA0/eA1 (CSR build precedes e-buffer writes)
  unsigned* pairbuf = (unsigned*)eA0;
  int* rowptr[4]; unsigned short* tsorted[4];
  for (int r = 0; r < 4; ++r) {
    rowptr[r]  = (int*)alloc((NN + 1) * sizeof(int));
    tsorted[r] = (unsigned short*)alloc((size_t)EE * sizeof(unsigned short));
  }
  int* bcnt  = (int*)alloc(((size_t)4 * NBK + 64) * sizeof(int));
  int* semctr = bcnt + 4 * NBK;          // zeroed together with bcnt
  int* bbase = (int*)alloc((size_t)4 * (NBK + 1) * sizeof(int));
  int* bcur  = (int*)alloc((size_t)4 * NBK * sizeof(int));
  float* x1all = (float*)alloc((size_t)4 * NHOP * NN * sizeof(float));
  float* w2all = (float*)alloc((size_t)4 * NHOP * NN * sizeof(float));
  float* h1b[4];
  for (int r = 0; r < 4; ++r) h1b[r] = (float*)alloc(NN * sizeof(float));
  float* psums = (float*)alloc((size_t)2 * NBK * 2 * sizeof(float));
  float* betab = (float*)alloc(64);

  // ---- projections (both sides, one dispatch, 32-row tiles -> 2500 blocks) ----
  proj_gemm_relu2<<<dim3(NN / 32, 2), 128, 0, stream>>>(
      x_author, W1_a, b1_a, xA, xA16,
      x_paper,  W1_p, b1_p, xP, xP16);

  // ---- CSR build (bucket-level counting; no per-node global histogram) ----
  const int NEB = (EE + BINCH - 1) / BINCH;
  zero_i32<<<(4 * NBK + 64 + 255) / 256, 256, 0, stream>>>(bcnt, 4 * NBK + 64);
  binCount_kernel<<<dim3(NEB, 4), 256, 0, stream>>>(ei[0], ei[1], ei[2], ei[3], bcnt, EE);
  bucketScan_kernel<<<4, 1024, 0, stream>>>(bcnt, bbase, bcur,
      rowptr[0], rowptr[1], rowptr[2], rowptr[3], EE);
  binA_kernel<<<dim3(NEB, 4), 256, 0, stream>>>(
      ei[0], ei[1], ei[2], ei[3], bcur, pairbuf, EE);
  binB_kernel<<<dim3(NBK, 4), 256, 0, stream>>>(pairbuf, bbase,
      rowptr[0], rowptr[1], rowptr[2], rowptr[3],
      tsorted[0], tsorted[1], tsorted[2], tsorted[3], EE);

  // ---- upfront x1/w2 (all hops) + hop-0 h1 (thread-per-node) ----
  precompute_xw<<<dim3((NN + 255) / 256, 2), 256, 0, stream>>>(
      xA, xP, a1_ap, a2_ap, a1_aa, a2_aa, a1_pa, a2_pa, a1_pp, a2_pp,
      x1all, w2all, h1b[0], h1b[1], h1b[2], h1b[3]);

  // ---- hop loop ----
  const int CVEC = NN * DD / 4;
  for (int i = 0; i < NHOP; ++i) {
    #define X1(r) (x1all + ((size_t)(r) * NHOP + i) * NN)
    #define W2P(r) (w2all + ((size_t)(r) * NHOP + i) * NN)
    AggRel r0 = {xA, (const __half2*)hP16, X1(0), W2P(0), h1b[0], rowptr[0], tsorted[0], eA0};
    AggRel r1 = {xA, (const __half2*)hA16, X1(1), W2P(1), h1b[1], rowptr[1], tsorted[1], eA1};
    AggRel r2 = {xP, (const __half2*)hA16, X1(2), W2P(2), h1b[2], rowptr[2], tsorted[2], eP0};
    AggRel r3 = {xP, (const __half2*)hP16, X1(3), W2P(3), h1b[3], rowptr[3], tsorted[3], eP1};
    agg4_kernel<<<NN, 256, 0, stream>>>(r0, r1, r2, r3, NN);

    sem_kernel<<<dim3(NN / 64, 2), 256, 0, stream>>>(
        eA0, eA1, eP0, eP1,
        semW_a + (size_t)i * DD * NSEM, semb_a + i * NSEM, semq_a + i * NSEM,
        semW_p + (size_t)i * DD * NSEM, semb_p + i * NSEM, semq_p + i * NSEM,
        psums, betab, semctr);

    int inext = (i + 1 < NHOP) ? (i + 1) : i;
    combine2_kernel<<<dim3((CVEC + 255) / 256, 2), 256, 0, stream>>>(
        (const float4*)eA0, (const float4*)eA1, (const float4*)eP0, (const float4*)eP1,
        betab, (float4*)hA, (float4*)hP, (__half2*)hA16, (__half2*)hP16,
        a2_ap + inext * DD, a2_aa + inext * DD, a2_pa + inext * DD, a2_pp + inext * DD,
        h1b[0], h1b[1], h1b[2], h1b[3], (i + 1 < NHOP) ? 1 : 0, CVEC);
  }

  final_kernel<<<(NN + 255) / 256, 256, 0, stream>>>(hA, W2, b2, (float*)d_out, NN);
}

// Round 17
// 1143.121 us; speedup vs baseline: 1.2005x; 1.2005x over previous
//
#include <hip/hip_runtime.h>
#include <hip/hip_fp16.h>

#define NN 40000
#define DD 64
#define EE 800000
#define NHOP 5
#define NSEM 128
#define NBK 625          // NN/64 buckets for binned scatter
#define BINCH 8192       // edges per binA/binCount block

__device__ __forceinline__ float leaky02(float v) { return v > 0.f ? v : 0.2f * v; }
__device__ __forceinline__ float tanh_fast(float x) {
  return 1.f - 2.f / (__expf(2.f * x) + 1.f);
}
__device__ __forceinline__ float wred(float x) {
  #pragma unroll
  for (int m = 1; m < 64; m <<= 1) x += __shfl_xor(x, m);
  return x;
}

// ---------------- zero kernel ----------------
__global__ void zero_i32(int* __restrict__ p, int n) {
  int i = blockIdx.x * blockDim.x + threadIdx.x;
  if (i < n) p[i] = 0;
}

// ---------------- projection GEMM: 32x64 tile, BK=32, 128 thr, 4x4 acc ----------------
#define PBK 32
__global__ __launch_bounds__(128) void proj_gemm_relu2(
    const float* __restrict__ Xa, const float* __restrict__ Wa,
    const float* __restrict__ ba, float* __restrict__ oa, __half* __restrict__ oa16,
    const float* __restrict__ Xp, const float* __restrict__ Wp,
    const float* __restrict__ bp, float* __restrict__ op, __half* __restrict__ op16)
{
  int side = blockIdx.y;
  const float* X = side ? Xp : Xa;
  const float* W = side ? Wp : Wa;
  const float* bias = side ? bp : ba;
  float* out = side ? op : oa;
  __half* out16 = side ? op16 : oa16;
  int K = side ? 512 : 334;

  __shared__ float As[32][PBK + 1];
  __shared__ float Bs[PBK][DD];
  int tid = threadIdx.x;
  int tx = tid & 15;       // col quad (4 cols)
  int ty = tid >> 4;       // row quad (4 rows), 0..7
  int row0 = blockIdx.x * 32;
  float acc[4][4] = {{0.f}};
  int nk = (K + PBK - 1) / PBK;
  for (int kt = 0; kt < nk; ++kt) {
    int k0 = kt * PBK;
    #pragma unroll
    for (int j = 0; j < 8; ++j) {
      int idx = tid + j * 128;
      int r = idx >> 5, c = idx & 31;
      int gk = k0 + c;
      As[r][c] = (gk < K) ? X[(size_t)(row0 + r) * K + gk] : 0.f;
    }
    #pragma unroll
    for (int j = 0; j < 4; ++j) {
      int idx = tid + j * 128;
      int r = idx >> 4, c4 = idx & 15;
      int gk = k0 + r;
      float4 v = (gk < K) ? ((const float4*)(W + (size_t)gk * DD))[c4]
                          : make_float4(0.f, 0.f, 0.f, 0.f);
      ((float4*)&Bs[r][0])[c4] = v;
    }
    __syncthreads();
    #pragma unroll 8
    for (int kk = 0; kk < PBK; ++kk) {
      float a0 = As[ty * 4 + 0][kk];
      float a1 = As[ty * 4 + 1][kk];
      float a2 = As[ty * 4 + 2][kk];
      float a3 = As[ty * 4 + 3][kk];
      float4 bv = ((float4*)&Bs[kk][0])[tx];
      acc[0][0] = fmaf(a0, bv.x, acc[0][0]);
      acc[0][1] = fmaf(a0, bv.y, acc[0][1]);
      acc[0][2] = fmaf(a0, bv.z, acc[0][2]);
      acc[0][3] = fmaf(a0, bv.w, acc[0][3]);
      acc[1][0] = fmaf(a1, bv.x, acc[1][0]);
      acc[1][1] = fmaf(a1, bv.y, acc[1][1]);
      acc[1][2] = fmaf(a1, bv.z, acc[1][2]);
      acc[1][3] = fmaf(a1, bv.w, acc[1][3]);
      acc[2][0] = fmaf(a2, bv.x, acc[2][0]);
      acc[2][1] = fmaf(a2, bv.y, acc[2][1]);
      acc[2][2] = fmaf(a2, bv.z, acc[2][2]);
      acc[2][3] = fmaf(a2, bv.w, acc[2][3]);
      acc[3][0] = fmaf(a3, bv.x, acc[3][0]);
      acc[3][1] = fmaf(a3, bv.y, acc[3][1]);
      acc[3][2] = fmaf(a3, bv.z, acc[3][2]);
      acc[3][3] = fmaf(a3, bv.w, acc[3][3]);
    }
    __syncthreads();
  }
  float4 bb = ((const float4*)bias)[tx];
  #pragma unroll
  for (int i = 0; i < 4; ++i) {
    int gr = row0 + ty * 4 + i;
    float4 v;
    v.x = fmaxf(acc[i][0] + bb.x, 0.f);
    v.y = fmaxf(acc[i][1] + bb.y, 0.f);
    v.z = fmaxf(acc[i][2] + bb.z, 0.f);
    v.w = fmaxf(acc[i][3] + bb.w, 0.f);
    ((float4*)(out + (size_t)gr * DD))[tx] = v;
    __half2 p0 = __floats2half2_rn(v.x, v.y);
    __half2 p1 = __floats2half2_rn(v.z, v.w);
    ((__half2*)(out16 + (size_t)gr * DD))[tx * 2 + 0] = p0;
    ((__half2*)(out16 + (size_t)gr * DD))[tx * 2 + 1] = p1;
  }
}

// ---------------- CSR build: bucket counts (LDS-privatized) ----------------
__global__ __launch_bounds__(256) void binCount_kernel(
    const int* __restrict__ e0, const int* __restrict__ e1,
    const int* __restrict__ e2, const int* __restrict__ e3,
    int* __restrict__ bcnt, int e)
{
  int rel = blockIdx.y;
  const int* S = rel == 0 ? e0 : rel == 1 ? e1 : rel == 2 ? e2 : e3;
  __shared__ int cnt[NBK];
  int tid = threadIdx.x;
  for (int b = tid; b < NBK; b += 256) cnt[b] = 0;
  __syncthreads();
  int e0i = blockIdx.x * BINCH;
  int ne = min(BINCH, e - e0i);
  for (int i = tid; i < ne; i += 256) atomicAdd(&cnt[S[e0i + i] >> 6], 1);
  __syncthreads();
  for (int b = tid; b < NBK; b += 256)
    if (cnt[b]) atomicAdd(&bcnt[rel * NBK + b], cnt[b]);
}

// bucket scan -> bucket bases + cursor seed; also sets rowptr[NN]=E
__global__ __launch_bounds__(1024) void bucketScan_kernel(
    const int* __restrict__ bcnt, int* __restrict__ bbase, int* __restrict__ bcur,
    int* __restrict__ rp0, int* __restrict__ rp1, int* __restrict__ rp2,
    int* __restrict__ rp3, int e)
{
  int rel = blockIdx.x;
  __shared__ int sh[1024];
  int t = threadIdx.x;
  int v = (t < NBK) ? bcnt[rel * NBK + t] : 0;
  sh[t] = v;
  __syncthreads();
  for (int off = 1; off < 1024; off <<= 1) {
    int y = (t >= off) ? sh[t - off] : 0;
    __syncthreads();
    sh[t] += y;
    __syncthreads();
  }
  if (t < NBK) {
    int base = sh[t] - v;
    bbase[rel * (NBK + 1) + t] = base;
    bcur[rel * NBK + t] = base;
  }
  if (t == 0) {
    bbase[rel * (NBK + 1) + NBK] = e;
    (rel == 0 ? rp0 : rel == 1 ? rp1 : rel == 2 ? rp2 : rp3)[NN] = e;
  }
}

// pass A: bin edges into buckets, packed u32 = (s&63)<<16 | t
__global__ __launch_bounds__(256) void binA_kernel(
    const int* __restrict__ e0, const int* __restrict__ e1,
    const int* __restrict__ e2, const int* __restrict__ e3,
    int* __restrict__ bcur, unsigned* __restrict__ pairbuf, int e)
{
  int rel = blockIdx.y;
  const int* S = rel == 0 ? e0 : rel == 1 ? e1 : rel == 2 ? e2 : e3;
  const int* T = S + e;
  unsigned* pb = pairbuf + (size_t)rel * e;
  __shared__ int cnt[NBK], base[NBK], cnt2[NBK];
  int tid = threadIdx.x;
  for (int b = tid; b < NBK; b += 256) { cnt[b] = 0; cnt2[b] = 0; }
  __syncthreads();
  int e0i = blockIdx.x * BINCH;
  int ne = min(BINCH, e - e0i);
  for (int i = tid; i < ne; i += 256) atomicAdd(&cnt[S[e0i + i] >> 6], 1);
  __syncthreads();
  for (int b = tid; b < NBK; b += 256)
    base[b] = cnt[b] ? atomicAdd(&bcur[rel * NBK + b], cnt[b]) : 0;
  __syncthreads();
  for (int i = tid; i < ne; i += 256) {
    int s = S[e0i + i];
    int t = T[e0i + i];
    int b = s >> 6;
    int off = atomicAdd(&cnt2[b], 1);
    pb[base[b] + off] = ((unsigned)(s & 63) << 16) | (unsigned)t;
  }
}

// pass B: per bucket — local per-node counts, wave prefix -> rowptr, place targets (u16)
__global__ __launch_bounds__(256) void binB_kernel(
    const unsigned* __restrict__ pairbuf, const int* __restrict__ bbase,
    int* __restrict__ rp0, int* __restrict__ rp1, int* __restrict__ rp2,
    int* __restrict__ rp3,
    unsigned short* __restrict__ ts0, unsigned short* __restrict__ ts1,
    unsigned short* __restrict__ ts2, unsigned short* __restrict__ ts3, int e)
{
  int rel = blockIdx.y;
  int* rowptr = rel == 0 ? rp0 : rel == 1 ? rp1 : rel == 2 ? rp2 : rp3;
  unsigned short* ts = rel == 0 ? ts0 : rel == 1 ? ts1 : rel == 2 ? ts2 : ts3;
  const unsigned* pb = pairbuf + (size_t)rel * e;
  int b = blockIdx.x;
  int bstart = bbase[rel * (NBK + 1) + b];
  int bend   = bbase[rel * (NBK + 1) + b + 1];
  __shared__ int ncnt[64], cur[64];
  int tid = threadIdx.x;
  if (tid < 64) ncnt[tid] = 0;
  __syncthreads();
  for (int i = bstart + tid; i < bend; i += 256)
    atomicAdd(&ncnt[(pb[i] >> 16) & 63], 1);
  __syncthreads();
  if (tid < 64) {                       // wave 0: 64-wide inclusive scan
    int v = ncnt[tid];
    int x = v;
    #pragma unroll
    for (int off = 1; off < 64; off <<= 1) {
      int y = __shfl_up(x, off);
      if (tid >= off) x += y;
    }
    int nb = bstart + x - v;            // exclusive prefix
    rowptr[b * 64 + tid] = nb;
    cur[tid] = nb;
  }
  __syncthreads();
  for (int i = bstart + tid; i < bend; i += 256) {
    unsigned u = pb[i];
    int pos = atomicAdd(&cur[(u >> 16) & 63], 1);
    ts[pos] = (unsigned short)(u & 0xffffu);
  }
}

// ---------------- upfront x1/w2 (all hops) + hop-0 h1 : thread-per-node ----------------
__global__ __launch_bounds__(256) void precompute_xw(
    const float* __restrict__ xA, const float* __restrict__ xP,
    const float* __restrict__ a1_ap, const float* __restrict__ a2_ap,
    const float* __restrict__ a1_aa, const float* __restrict__ a2_aa,
    const float* __restrict__ a1_pa, const float* __restrict__ a2_pa,
    const float* __restrict__ a1_pp, const float* __restrict__ a2_pp,
    float* __restrict__ x1all, float* __restrict__ w2all,
    float* __restrict__ h1_ap, float* __restrict__ h1_aa,
    float* __restrict__ h1_pa, float* __restrict__ h1_pp)
{
  int side = blockIdx.y;
  __shared__ float L[21 * DD];
  int tid = threadIdx.x;
  {
    const float* s0 = side ? a1_pa : a1_ap;
    const float* s1 = side ? a2_pa : a2_ap;
    const float* s2 = side ? a1_pp : a1_aa;
    const float* s3 = side ? a2_pp : a2_aa;
    const float* ex = side ? a2_ap : a2_pa;   // hop-0 cross-side extra
    for (int i = tid; i < 21 * DD; i += 256) {
      int k = i >> 6, d = i & 63;
      const float* src = (k < 5) ? s0 : (k < 10) ? s1 : (k < 15) ? s2 : (k < 20) ? s3 : ex;
      int hop = (k < 20) ? (k % 5) : 0;
      L[i] = src[hop * DD + d];
    }
  }
  __syncthreads();
  int j = blockIdx.x * 256 + tid;
  if (j >= NN) return;
  const float4* x4 = (const float4*)((side ? xP : xA) + (size_t)j * DD);
  float acc[21];
  #pragma unroll
  for (int k = 0; k < 21; ++k) acc[k] = 0.f;
  #pragma unroll
  for (int d0 = 0; d0 < 16; ++d0) {
    float4 v = x4[d0];
    #pragma unroll
    for (int c = 0; c < 4; ++c) {
      int d = d0 * 4 + c;
      float xv = (&v.x)[c];
      #pragma unroll
      for (int k = 0; k < 21; ++k) acc[k] = fmaf(xv, L[k * DD + d], acc[k]);
    }
  }
  int relA = side ? 2 : 0;
  #pragma unroll
  for (int i = 0; i < NHOP; ++i) {
    x1all[((size_t)(relA + 0) * NHOP + i) * NN + j] = acc[0 * 5 + i];
    w2all[((size_t)(relA + 0) * NHOP + i) * NN + j] =
        __expf(leaky02(acc[0 * 5 + i] + acc[1 * 5 + i]));
    x1all[((size_t)(relA + 1) * NHOP + i) * NN + j] = acc[2 * 5 + i];
    w2all[((size_t)(relA + 1) * NHOP + i) * NN + j] =
        __expf(leaky02(acc[2 * 5 + i] + acc[3 * 5 + i]));
  }
  if (side) { h1_pp[j] = acc[15]; h1_ap[j] = acc[20]; }
  else      { h1_aa[j] = acc[15]; h1_pa[j] = acc[20]; }
}

// ---------------- fused edge aggregation: 8-deep half2 gathers + XCD partition ----------------
struct AggRel {
  const float* x; const __half2* h2; const float* x1; const float* w2; const float* h1;
  const int* rowptr; const unsigned short* tsorted; float* out;
};

__global__ __launch_bounds__(256) void agg4_kernel(AggRel r0, AggRel r1, AggRel r2,
                                                   AggRel r3, int n)
{
  int bid = blockIdx.x;
  int g = (bid >> 2) & 1;
  int u = (bid >> 3) * 4 + (bid & 3);       // 0 .. n/2-1
  int half = n >> 2;                        // blocks per relation (10000)
  int relsel = u >= half;
  int nodeblk = relsel ? (u - half) : u;
  AggRel R;
  if (g == 0) R = relsel ? r2 : r1;
  else        R = relsel ? r3 : r0;

  int wid = nodeblk * 4 + (threadIdx.x >> 6);
  int lane = threadIdx.x & 63;
  int pair = lane >> 5;        // 0: even edges, 1: odd edges
  int c2 = lane & 31;          // half2 column index (cols 2*c2, 2*c2+1)

  int beg = R.rowptr[wid], end = R.rowptr[wid + 1];
  float x1i = R.x1[wid];
  float2 a0v = make_float2(0.f, 0.f), a1v = make_float2(0.f, 0.f);
  float2 a2v = make_float2(0.f, 0.f), a3v = make_float2(0.f, 0.f);
  float2 a4v = make_float2(0.f, 0.f), a5v = make_float2(0.f, 0.f);
  float2 a6v = make_float2(0.f, 0.f), a7v = make_float2(0.f, 0.f);
  float wsumL = 0.f;
  for (int c = beg; c < end; c += 64) {
    int idx = c + lane;
    int t = 0;
    float wv = 0.f;
    if (idx < end) {
      t = R.tsorted[idx];
      wv = __expf(leaky02(x1i + R.h1[t]));
    }
    wsumL += wv;
    int ne = min(64, end - c);
    for (int j = 0; j < ne; j += 16) {     // phantom edges: wv==0, t==0 (safe)
      int s0 = j + pair,      s1 = j + 2 + pair,  s2 = j + 4 + pair,  s3 = j + 6 + pair;
      int s4 = j + 8 + pair,  s5 = j + 10 + pair, s6 = j + 12 + pair, s7 = j + 14 + pair;
      int t0 = __shfl(t, s0), t1 = __shfl(t, s1), t2 = __shfl(t, s2), t3 = __shfl(t, s3);
      int t4 = __shfl(t, s4), t5 = __shfl(t, s5), t6 = __shfl(t, s6), t7 = __shfl(t, s7);
      float w0 = __shfl(wv, s0), w1 = __shfl(wv, s1), w2_ = __shfl(wv, s2), w3 = __shfl(wv, s3);
      float w4 = __shfl(wv, s4), w5 = __shfl(wv, s5), w6 = __shfl(wv, s6), w7 = __shfl(wv, s7);
      float2 f0 = __half22float2(R.h2[((unsigned)t0 << 5) + c2]);
      float2 f1 = __half22float2(R.h2[((unsigned)t1 << 5) + c2]);
      float2 f2 = __half22float2(R.h2[((unsigned)t2 << 5) + c2]);
      float2 f3 = __half22float2(R.h2[((unsigned)t3 << 5) + c2]);
      float2 f4 = __half22float2(R.h2[((unsigned)t4 << 5) + c2]);
      float2 f5 = __half22float2(R.h2[((unsigned)t5 << 5) + c2]);
      float2 f6 = __half22float2(R.h2[((unsigned)t6 << 5) + c2]);
      float2 f7 = __half22float2(R.h2[((unsigned)t7 << 5) + c2]);
      a0v.x = fmaf(w0, f0.x, a0v.x);  a0v.y = fmaf(w0, f0.y, a0v.y);
      a1v.x = fmaf(w1, f1.x, a1v.x);  a1v.y = fmaf(w1, f1.y, a1v.y);
      a2v.x = fmaf(w2_, f2.x, a2v.x); a2v.y = fmaf(w2_, f2.y, a2v.y);
      a3v.x = fmaf(w3, f3.x, a3v.x);  a3v.y = fmaf(w3, f3.y, a3v.y);
      a4v.x = fmaf(w4, f4.x, a4v.x);  a4v.y = fmaf(w4, f4.y, a4v.y);
      a5v.x = fmaf(w5, f5.x, a5v.x);  a5v.y = fmaf(w5, f5.y, a5v.y);
      a6v.x = fmaf(w6, f6.x, a6v.x);  a6v.y = fmaf(w6, f6.y, a6v.y);
      a7v.x = fmaf(w7, f7.x, a7v.x);  a7v.y = fmaf(w7, f7.y, a7v.y);
    }
  }
  float wsum = wred(wsumL);
  float2 acc;
  acc.x = ((a0v.x + a1v.x) + (a2v.x + a3v.x)) + ((a4v.x + a5v.x) + (a6v.x + a7v.x));
  acc.y = ((a0v.y + a1v.y) + (a2v.y + a3v.y)) + ((a4v.y + a5v.y) + (a6v.y + a7v.y));
  acc.x += __shfl_xor(acc.x, 32);            // fold odd-edge half into even half
  acc.y += __shfl_xor(acc.y, 32);
  if (pair == 0) {
    float w2v = R.w2[wid];
    float inv = 1.f / (wsum + w2v);
    float2 xv = ((const float2*)(R.x + (size_t)wid * DD))[c2];
    float2 o;
    o.x = fmaf(w2v, xv.x, acc.x) * inv;
    o.y = fmaf(w2v, xv.y, acc.y) * inv;
    ((float2*)(R.out + (size_t)wid * DD))[c2] = o;
  }
}

// ---------------- semantic attention partial sums (transposed z, pad 13, conflict-free) ----------------
__global__ __launch_bounds__(256) void sem_kernel(
    const float* __restrict__ eA0, const float* __restrict__ eA1,
    const float* __restrict__ eP0, const float* __restrict__ eP1,
    const float* __restrict__ Wa, const float* __restrict__ ba, const float* __restrict__ qa,
    const float* __restrict__ Wp, const float* __restrict__ bp, const float* __restrict__ qp,
    float* __restrict__ psums)
{
  int side = blockIdx.y;
  const float* e0 = side ? eP0 : eA0;
  const float* e1 = side ? eP1 : eA1;
  const float* W = side ? Wp : Wa;
  const float* b = side ? bp : ba;
  const float* q = side ? qp : qa;

  __shared__ float Ws[DD * NSEM];
  __shared__ float zt[2][DD][13];        // 8 nodes transposed, pad 13 (gcd(13,32)=1)
  __shared__ float red0[256], red1[256];
  int tid = threadIdx.x;
  {
    const float4* W4 = (const float4*)W;
    float4* Ws4 = (float4*)Ws;
    #pragma unroll
    for (int j = 0; j < 8; ++j) Ws4[tid + j * 256] = W4[tid + j * 256];
  }
  int slot = tid >> 7;                   // 2 slots x 4 nodes
  int k = tid & 127;
  float bk = b[k], qk = q[k];
  int base = blockIdx.x * 64;
  float sum0 = 0.f, sum1 = 0.f;
  for (int it = 0; it < 8; ++it) {
    #pragma unroll
    for (int j = 0; j < 4; ++j) {
      int idx = tid + j * 256;
      int d = idx & 63, m = (idx >> 6) & 1, nn = idx >> 7;
      zt[m][d][nn] = (m ? e1 : e0)[(size_t)(base + it * 8 + nn) * DD + d];
    }
    __syncthreads();
    float a0[4], a1[4];
    #pragma unroll
    for (int nn = 0; nn < 4; ++nn) { a0[nn] = bk; a1[nn] = bk; }
    #pragma unroll 8
    for (int d = 0; d < DD; ++d) {
      float w = Ws[d * NSEM + k];
      #pragma unroll
      for (int nn = 0; nn < 4; ++nn) {
        a0[nn] = fmaf(zt[0][d][slot * 4 + nn], w, a0[nn]);
        a1[nn] = fmaf(zt[1][d][slot * 4 + nn], w, a1[nn]);
      }
    }
    #pragma unroll
    for (int nn = 0; nn < 4; ++nn) {
      sum0 += tanh_fast(a0[nn]) * qk;
      sum1 += tanh_fast(a1[nn]) * qk;
    }
    __syncthreads();
  }
  red0[tid] = sum0;
  red1[tid] = sum1;
  __syncthreads();
  for (int off = 128; off; off >>= 1) {
    if (tid < off) { red0[tid] += red0[tid + off]; red1[tid] += red1[tid + off]; }
    __syncthreads();
  }
  if (tid == 0) {
    int idx = (side * gridDim.x + blockIdx.x) * 2;
    psums[idx + 0] = red0[0];
    psums[idx + 1] = red1[0];
  }
}

__global__ __launch_bounds__(256) void beta_kernel(const float* __restrict__ psums,
    float* __restrict__ beta, int nblk, float invn)
{
  __shared__ float s[4][256];
  int t = threadIdx.x;
  float a0 = 0.f, a1 = 0.f, p0 = 0.f, p1 = 0.f;
  for (int i = t; i < nblk; i += 256) {
    a0 += psums[i * 2];
    a1 += psums[i * 2 + 1];
    p0 += psums[(nblk + i) * 2];
    p1 += psums[(nblk + i) * 2 + 1];
  }
  s[0][t] = a0; s[1][t] = a1; s[2][t] = p0; s[3][t] = p1;
  __syncthreads();
  for (int off = 128; off; off >>= 1) {
    if (t < off) {
      s[0][t] += s[0][t + off]; s[1][t] += s[1][t + off];
      s[2][t] += s[2][t + off]; s[3][t] += s[3][t + off];
    }
    __syncthreads();
  }
  if (t == 0) {
    float m0 = s[0][0] * invn, m1 = s[1][0] * invn;
    float mx = fmaxf(m0, m1);
    float x0 = __expf(m0 - mx), x1 = __expf(m1 - mx);
    float inv = 1.f / (x0 + x1);
    beta[0] = x0 * inv; beta[1] = x1 * inv;
    m0 = s[2][0] * invn; m1 = s[3][0] * invn;
    mx = fmaxf(m0, m1);
    x0 = __expf(m0 - mx); x1 = __expf(m1 - mx);
    inv = 1.f / (x0 + x1);
    beta[2] = x0 * inv; beta[3] = x1 * inv;
  }
}

// ---------------- combine + ELU + fp16 copy + fused next-hop h1 (shfl 16-lane dots) ----------------
__global__ void combine2_kernel(const float4* __restrict__ eA0, const float4* __restrict__ eA1,
    const float4* __restrict__ eP0, const float4* __restrict__ eP1,
    const float* __restrict__ beta, float4* __restrict__ hA, float4* __restrict__ hP,
    __half2* __restrict__ hA16, __half2* __restrict__ hP16,
    const float* __restrict__ a2_ap_n, const float* __restrict__ a2_aa_n,
    const float* __restrict__ a2_pa_n, const float* __restrict__ a2_pp_n,
    float* __restrict__ h1_ap, float* __restrict__ h1_aa,
    float* __restrict__ h1_pa, float* __restrict__ h1_pp,
    int has_next, int nvec)
{
  int side = blockIdx.y;
  int i = blockIdx.x * 256 + threadIdx.x;
  if (i >= nvec) return;
  float b0 = beta[side * 2], b1 = beta[side * 2 + 1];
  float4 v0 = (side ? eP0 : eA0)[i];
  float4 v1 = (side ? eP1 : eA1)[i];
  float4 r;
  float t;
  t = b0 * v0.x + b1 * v1.x; r.x = t > 0.f ? t : (__expf(t) - 1.f);
  t = b0 * v0.y + b1 * v1.y; r.y = t > 0.f ? t : (__expf(t) - 1.f);
  t = b0 * v0.z + b1 * v1.z; r.z = t > 0.f ? t : (__expf(t) - 1.f);
  t = b0 * v0.w + b1 * v1.w; r.w = t > 0.f ? t : (__expf(t) - 1.f);
  (side ? hP : hA)[i] = r;
  (side ? hP16 : hA16)[i * 2 + 0] = __floats2half2_rn(r.x, r.y);
  (side ? hP16 : hA16)[i * 2 + 1] = __floats2half2_rn(r.z, r.w);
  if (has_next) {
    // row = i>>4; its 16 float4-threads are consecutive lanes in one wave
    int col4 = i & 15;
    const float* ax = side ? a2_ap_n : a2_aa_n;
    const float* ay = side ? a2_pp_n : a2_pa_n;
    float4 a4 = ((const float4*)ax)[col4];
    float4 c4 = ((const float4*)ay)[col4];
    float rx = r.x * a4.x + r.y * a4.y + r.z * a4.z + r.w * a4.w;
    float ry = r.x * c4.x + r.y * c4.y + r.z * c4.z + r.w * c4.w;
    #pragma unroll
    for (int m = 1; m < 16; m <<= 1) {
      rx += __shfl_xor(rx, m);
      ry += __shfl_xor(ry, m);
    }
    if ((threadIdx.x & 15) == 0) {
      int row = i >> 4;
      if (side) { h1_ap[row] = rx; h1_pp[row] = ry; }
      else      { h1_aa[row] = rx; h1_pa[row] = ry; }
    }
  }
}

// ---------------- final projection ----------------
__global__ void final_kernel(const float* __restrict__ hA, const float* __restrict__ W2,
    const float* __restrict__ b2, float* __restrict__ out, int n)
{
  int j = blockIdx.x * blockDim.x + threadIdx.x;
  if (j >= n) return;
  float acc0 = b2[0], acc1 = b2[1], acc2 = b2[2], acc3 = b2[3];
  const float4* hrow = (const float4*)(hA + (size_t)j * DD);
  #pragma unroll
  for (int d4 = 0; d4 < 16; ++d4) {
    float4 v = hrow[d4];
    #pragma unroll
    for (int c = 0; c < 4; ++c) {
      int d = d4 * 4 + c;
      float vv = (&v.x)[c];
      acc0 = fmaf(vv, W2[d * 4 + 0], acc0);
      acc1 = fmaf(vv, W2[d * 4 + 1], acc1);
      acc2 = fmaf(vv, W2[d * 4 + 2], acc2);
      acc3 = fmaf(vv, W2[d * 4 + 3], acc3);
    }
  }
  ((float4*)out)[j] = make_float4(acc0, acc1, acc2, acc3);
}

extern "C" void kernel_launch(void* const* d_in, const int* in_sizes, int n_in,
                              void* d_out, int out_size, void* d_ws, size_t ws_size,
                              hipStream_t stream)
{
  const float* x_author = (const float*)d_in[0];
  const float* x_paper  = (const float*)d_in[1];
  const float* W1_a = (const float*)d_in[2];
  const float* b1_a = (const float*)d_in[3];
  const float* W1_p = (const float*)d_in[4];
  const float* b1_p = (const float*)d_in[5];
  const float* a1_ap = (const float*)d_in[6];
  const float* a2_ap = (const float*)d_in[7];
  const float* a1_aa = (const float*)d_in[8];
  const float* a2_aa = (const float*)d_in[9];
  const float* a1_pa = (const float*)d_in[10];
  const float* a2_pa = (const float*)d_in[11];
  const float* a1_pp = (const float*)d_in[12];
  const float* a2_pp = (const float*)d_in[13];
  const float* semW_a = (const float*)d_in[14];
  const float* semb_a = (const float*)d_in[15];
  const float* semq_a = (const float*)d_in[16];
  const float* semW_p = (const float*)d_in[17];
  const float* semb_p = (const float*)d_in[18];
  const float* semq_p = (const float*)d_in[19];
  const float* W2 = (const float*)d_in[20];
  const float* b2 = (const float*)d_in[21];
  const int* ei[4] = {(const int*)d_in[22], (const int*)d_in[23],
                      (const int*)d_in[24], (const int*)d_in[25]};

  // ---- workspace carve ----
  char* w = (char*)d_ws;
  auto alloc = [&](size_t bytes) -> void* {
    void* p = (void*)w;
    w += (bytes + 255) & ~(size_t)255;
    return p;
  };
  const size_t matB = (size_t)NN * DD * sizeof(float);
  float* xA  = (float*)alloc(matB);
  float* xP  = (float*)alloc(matB);
  float* hA  = (float*)alloc(matB);
  float* hP  = (float*)alloc(matB);
  float* eA0 = (float*)alloc(matB);
  float* eA1 = (float*)alloc(matB);
  float* eP0 = (float*)alloc(matB);
  float* eP1 = (float*)alloc(matB);
  // fp16 gather buffers; hA16 aliases xA16 (proj rewrites each call before use)
  __half* xA16 = (__half*)alloc(matB / 2);
  __half* xP16 = (__half*)alloc(matB / 2);
  __half* hA16 = xA16;
  __half* hP16 = xP16;
  // pairbuf (4*E u32 = 12.8 MB) aliases eA0/eA1 (CSR build precedes e-buffer writes)
  unsigned* pairbuf = (unsigned*)eA0;
  int* rowptr[4]; unsigned short* tsorted[4];
  for (int r = 0; r < 4; ++r) {
    rowptr[r]  = (int*)alloc((NN + 1) * sizeof(int));
    tsorted[r] = (unsigned short*)alloc((size_t)EE * sizeof(unsigned short));
  }
  int* bcnt  = (int*)alloc((size_t)4 * NBK * sizeof(int));
  int* bbase = (int*)alloc((size_t)4 * (NBK + 1) * sizeof(int));
  int* bcur  = (int*)alloc((size_t)4 * NBK * sizeof(int));
  float* x1all = (float*)alloc((size_t)4 * NHOP * NN * sizeof(float));
  float* w2all = (float*)alloc((size_t)4 * NHOP * NN * sizeof(float));
  float* h1b[4];
  for (int r = 0; r < 4; ++r) h1b[r] = (float*)alloc(NN * sizeof(float));
  float* psums = (float*)alloc((size_t)2 * NBK * 2 * sizeof(float));
  float* betab = (float*)alloc(64);

  // ---- projections (both sides, one dispatch, 32-row tiles -> 2500 blocks) ----
  proj_gemm_relu2<<<dim3(NN / 32, 2), 128, 0, stream>>>(
      x_author, W1_a, b1_a, xA, xA16,
      x_paper,  W1_p, b1_p, xP, xP16);

  // ---- CSR build (bucket-level counting; no per-node global histogram) ----
  const int NEB = (EE + BINCH - 1) / BINCH;
  zero_i32<<<(4 * NBK + 255) / 256, 256, 0, stream>>>(bcnt, 4 * NBK);
  binCount_kernel<<<dim3(NEB, 4), 256, 0, stream>>>(ei[0], ei[1], ei[2], ei[3], bcnt, EE);
  bucketScan_kernel<<<4, 1024, 0, stream>>>(bcnt, bbase, bcur,
      rowptr[0], rowptr[1], rowptr[2], rowptr[3], EE);
  binA_kernel<<<dim3(NEB, 4), 256, 0, stream>>>(
      ei[0], ei[1], ei[2], ei[3], bcur, pairbuf, EE);
  binB_kernel<<<dim3(NBK, 4), 256, 0, stream>>>(pairbuf, bbase,
      rowptr[0], rowptr[1], rowptr[2], rowptr[3],
      tsorted[0], tsorted[1], tsorted[2], tsorted[3], EE);

  // ---- upfront x1/w2 (all hops) + hop-0 h1 (thread-per-node) ----
  precompute_xw<<<dim3((NN + 255) / 256, 2), 256, 0, stream>>>(
      xA, xP, a1_ap, a2_ap, a1_aa, a2_aa, a1_pa, a2_pa, a1_pp, a2_pp,
      x1all, w2all, h1b[0], h1b[1], h1b[2], h1b[3]);

  // ---- hop loop ----
  const int CVEC = NN * DD / 4;
  for (int i = 0; i < NHOP; ++i) {
    #define X1(r) (x1all + ((size_t)(r) * NHOP + i) * NN)
    #define W2P(r) (w2all + ((size_t)(r) * NHOP + i) * NN)
    AggRel r0 = {xA, (const __half2*)hP16, X1(0), W2P(0), h1b[0], rowptr[0], tsorted[0], eA0};
    AggRel r1 = {xA, (const __half2*)hA16, X1(1), W2P(1), h1b[1], rowptr[1], tsorted[1], eA1};
    AggRel r2 = {xP, (const __half2*)hA16, X1(2), W2P(2), h1b[2], rowptr[2], tsorted[2], eP0};
    AggRel r3 = {xP, (const __half2*)hP16, X1(3), W2P(3), h1b[3], rowptr[3], tsorted[3], eP1};
    agg4_kernel<<<NN, 256, 0, stream>>>(r0, r1, r2, r3, NN);

    sem_kernel<<<dim3(NN / 64, 2), 256, 0, stream>>>(
        eA0, eA1, eP0, eP1,
        semW_a + (size_t)i * DD * NSEM, semb_a + i * NSEM, semq_a + i * NSEM,
        semW_p + (size_t)i * DD * NSEM, semb_p + i * NSEM, semq_p + i * NSEM,
        psums);
    beta_kernel<<<1, 256, 0, stream>>>(psums, betab, NN / 64, 1.f / NN);

    int inext = (i + 1 < NHOP) ? (i + 1) : i;
    combine2_kernel<<<dim3((CVEC + 255) / 256, 2), 256, 0, stream>>>(
        (const float4*)eA0, (const float4*)eA1, (const float4*)eP0, (const float4*)eP1,
        betab, (float4*)hA, (float4*)hP, (__half2*)hA16, (__half2*)hP16,
        a2_ap + inext * DD, a2_aa + inext * DD, a2_pa + inext * DD, a2_pp + inext * DD,
        h1b[0], h1b[1], h1b[2], h1b[3], (i + 1 < NHOP) ? 1 : 0, CVEC);
  }

  final_kernel<<<(NN + 255) / 256, 256, 0, stream>>>(hA, W2, b2, (float*)d_out, NN);
}

// Round 18
// 938.471 us; speedup vs baseline: 1.4623x; 1.2181x over previous
//
#include <hip/hip_runtime.h>
#include <hip/hip_fp16.h>

#define NN 40000
#define DD 64
#define EE 800000
#define NHOP 5
#define NSEM 128
#define NBK 625          // NN/64 buckets for binned scatter
#define BINCH 8192       // edges per binA/binCount block

__device__ __forceinline__ float leaky02(float v) { return v > 0.f ? v : 0.2f * v; }
__device__ __forceinline__ float tanh_fast(float x) {
  return 1.f - 2.f / (__expf(2.f * x) + 1.f);
}
__device__ __forceinline__ float wred(float x) {
  #pragma unroll
  for (int m = 1; m < 64; m <<= 1) x += __shfl_xor(x, m);
  return x;
}

// ---------------- zero kernel ----------------
__global__ void zero_i32(int* __restrict__ p, int n) {
  int i = blockIdx.x * blockDim.x + threadIdx.x;
  if (i < n) p[i] = 0;
}

// ---------------- projection GEMM: 64x64 tile, BK=32, 256 thr, 4x4 acc (R15 best) ----------------
#define PBM 64
#define PBK 32
__global__ __launch_bounds__(256) void proj_gemm_relu2(
    const float* __restrict__ Xa, const float* __restrict__ Wa,
    const float* __restrict__ ba, float* __restrict__ oa, __half* __restrict__ oa16,
    const float* __restrict__ Xp, const float* __restrict__ Wp,
    const float* __restrict__ bp, float* __restrict__ op, __half* __restrict__ op16)
{
  int side = blockIdx.y;
  const float* X = side ? Xp : Xa;
  const float* W = side ? Wp : Wa;
  const float* bias = side ? bp : ba;
  float* out = side ? op : oa;
  __half* out16 = side ? op16 : oa16;
  int K = side ? 512 : 334;

  __shared__ float As[PBM][PBK + 1];
  __shared__ float Bs[PBK][DD];
  int tid = threadIdx.x;
  int tx = tid & 15;       // col quad (4 cols)
  int ty = tid >> 4;       // row quad (4 rows), 0..15
  int row0 = blockIdx.x * PBM;
  float acc[4][4] = {{0.f}};
  int nk = (K + PBK - 1) / PBK;
  for (int kt = 0; kt < nk; ++kt) {
    int k0 = kt * PBK;
    #pragma unroll
    for (int j = 0; j < 8; ++j) {
      int idx = tid + j * 256;
      int r = idx >> 5, c = idx & 31;
      int gk = k0 + c;
      As[r][c] = (gk < K) ? X[(size_t)(row0 + r) * K + gk] : 0.f;
    }
    #pragma unroll
    for (int j = 0; j < 2; ++j) {
      int idx = tid + j * 256;
      int r = idx >> 4, c4 = idx & 15;
      int gk = k0 + r;
      float4 v = (gk < K) ? ((const float4*)(W + (size_t)gk * DD))[c4]
                          : make_float4(0.f, 0.f, 0.f, 0.f);
      ((float4*)&Bs[r][0])[c4] = v;
    }
    __syncthreads();
    #pragma unroll 8
    for (int kk = 0; kk < PBK; ++kk) {
      float a0 = As[ty * 4 + 0][kk];
      float a1 = As[ty * 4 + 1][kk];
      float a2 = As[ty * 4 + 2][kk];
      float a3 = As[ty * 4 + 3][kk];
      float4 bv = ((float4*)&Bs[kk][0])[tx];
      acc[0][0] = fmaf(a0, bv.x, acc[0][0]);
      acc[0][1] = fmaf(a0, bv.y, acc[0][1]);
      acc[0][2] = fmaf(a0, bv.z, acc[0][2]);
      acc[0][3] = fmaf(a0, bv.w, acc[0][3]);
      acc[1][0] = fmaf(a1, bv.x, acc[1][0]);
      acc[1][1] = fmaf(a1, bv.y, acc[1][1]);
      acc[1][2] = fmaf(a1, bv.z, acc[1][2]);
      acc[1][3] = fmaf(a1, bv.w, acc[1][3]);
      acc[2][0] = fmaf(a2, bv.x, acc[2][0]);
      acc[2][1] = fmaf(a2, bv.y, acc[2][1]);
      acc[2][2] = fmaf(a2, bv.z, acc[2][2]);
      acc[2][3] = fmaf(a2, bv.w, acc[2][3]);
      acc[3][0] = fmaf(a3, bv.x, acc[3][0]);
      acc[3][1] = fmaf(a3, bv.y, acc[3][1]);
      acc[3][2] = fmaf(a3, bv.z, acc[3][2]);
      acc[3][3] = fmaf(a3, bv.w, acc[3][3]);
    }
    __syncthreads();
  }
  float4 bb = ((const float4*)bias)[tx];
  #pragma unroll
  for (int i = 0; i < 4; ++i) {
    int gr = row0 + ty * 4 + i;
    float4 v;
    v.x = fmaxf(acc[i][0] + bb.x, 0.f);
    v.y = fmaxf(acc[i][1] + bb.y, 0.f);
    v.z = fmaxf(acc[i][2] + bb.z, 0.f);
    v.w = fmaxf(acc[i][3] + bb.w, 0.f);
    ((float4*)(out + (size_t)gr * DD))[tx] = v;
    __half2 p0 = __floats2half2_rn(v.x, v.y);
    __half2 p1 = __floats2half2_rn(v.z, v.w);
    ((__half2*)(out16 + (size_t)gr * DD))[tx * 2 + 0] = p0;
    ((__half2*)(out16 + (size_t)gr * DD))[tx * 2 + 1] = p1;
  }
}

// ---------------- CSR build: bucket counts (LDS-privatized) ----------------
__global__ __launch_bounds__(256) void binCount_kernel(
    const int* __restrict__ e0, const int* __restrict__ e1,
    const int* __restrict__ e2, const int* __restrict__ e3,
    int* __restrict__ bcnt, int e)
{
  int rel = blockIdx.y;
  const int* S = rel == 0 ? e0 : rel == 1 ? e1 : rel == 2 ? e2 : e3;
  __shared__ int cnt[NBK];
  int tid = threadIdx.x;
  for (int b = tid; b < NBK; b += 256) cnt[b] = 0;
  __syncthreads();
  int e0i = blockIdx.x * BINCH;
  int ne = min(BINCH, e - e0i);
  for (int i = tid; i < ne; i += 256) atomicAdd(&cnt[S[e0i + i] >> 6], 1);
  __syncthreads();
  for (int b = tid; b < NBK; b += 256)
    if (cnt[b]) atomicAdd(&bcnt[rel * NBK + b], cnt[b]);
}

// bucket scan -> bucket bases + cursor seed; also sets rowptr[NN]=E
__global__ __launch_bounds__(1024) void bucketScan_kernel(
    const int* __restrict__ bcnt, int* __restrict__ bbase, int* __restrict__ bcur,
    int* __restrict__ rp0, int* __restrict__ rp1, int* __restrict__ rp2,
    int* __restrict__ rp3, int e)
{
  int rel = blockIdx.x;
  __shared__ int sh[1024];
  int t = threadIdx.x;
  int v = (t < NBK) ? bcnt[rel * NBK + t] : 0;
  sh[t] = v;
  __syncthreads();
  for (int off = 1; off < 1024; off <<= 1) {
    int y = (t >= off) ? sh[t - off] : 0;
    __syncthreads();
    sh[t] += y;
    __syncthreads();
  }
  if (t < NBK) {
    int base = sh[t] - v;
    bbase[rel * (NBK + 1) + t] = base;
    bcur[rel * NBK + t] = base;
  }
  if (t == 0) {
    bbase[rel * (NBK + 1) + NBK] = e;
    (rel == 0 ? rp0 : rel == 1 ? rp1 : rel == 2 ? rp2 : rp3)[NN] = e;
  }
}

// pass A: bin edges into buckets, packed u32 = (s&63)<<16 | t
__global__ __launch_bounds__(256) void binA_kernel(
    const int* __restrict__ e0, const int* __restrict__ e1,
    const int* __restrict__ e2, const int* __restrict__ e3,
    int* __restrict__ bcur, unsigned* __restrict__ pairbuf, int e)
{
  int rel = blockIdx.y;
  const int* S = rel == 0 ? e0 : rel == 1 ? e1 : rel == 2 ? e2 : e3;
  const int* T = S + e;
  unsigned* pb = pairbuf + (size_t)rel * e;
  __shared__ int cnt[NBK], base[NBK], cnt2[NBK];
  int tid = threadIdx.x;
  for (int b = tid; b < NBK; b += 256) { cnt[b] = 0; cnt2[b] = 0; }
  __syncthreads();
  int e0i = blockIdx.x * BINCH;
  int ne = min(BINCH, e - e0i);
  for (int i = tid; i < ne; i += 256) atomicAdd(&cnt[S[e0i + i] >> 6], 1);
  __syncthreads();
  for (int b = tid; b < NBK; b += 256)
    base[b] = cnt[b] ? atomicAdd(&bcur[rel * NBK + b], cnt[b]) : 0;
  __syncthreads();
  for (int i = tid; i < ne; i += 256) {
    int s = S[e0i + i];
    int t = T[e0i + i];
    int b = s >> 6;
    int off = atomicAdd(&cnt2[b], 1);
    pb[base[b] + off] = ((unsigned)(s & 63) << 16) | (unsigned)t;
  }
}

// pass B: per bucket — local per-node counts, wave prefix -> rowptr, place targets (u16)
__global__ __launch_bounds__(256) void binB_kernel(
    const unsigned* __restrict__ pairbuf, const int* __restrict__ bbase,
    int* __restrict__ rp0, int* __restrict__ rp1, int* __restrict__ rp2,
    int* __restrict__ rp3,
    unsigned short* __restrict__ ts0, unsigned short* __restrict__ ts1,
    unsigned short* __restrict__ ts2, unsigned short* __restrict__ ts3, int e)
{
  int rel = blockIdx.y;
  int* rowptr = rel == 0 ? rp0 : rel == 1 ? rp1 : rel == 2 ? rp2 : rp3;
  unsigned short* ts = rel == 0 ? ts0 : rel == 1 ? ts1 : rel == 2 ? ts2 : ts3;
  const unsigned* pb = pairbuf + (size_t)rel * e;
  int b = blockIdx.x;
  int bstart = bbase[rel * (NBK + 1) + b];
  int bend   = bbase[rel * (NBK + 1) + b + 1];
  __shared__ int ncnt[64], cur[64];
  int tid = threadIdx.x;
  if (tid < 64) ncnt[tid] = 0;
  __syncthreads();
  for (int i = bstart + tid; i < bend; i += 256)
    atomicAdd(&ncnt[(pb[i] >> 16) & 63], 1);
  __syncthreads();
  if (tid < 64) {                       // wave 0: 64-wide inclusive scan
    int v = ncnt[tid];
    int x = v;
    #pragma unroll
    for (int off = 1; off < 64; off <<= 1) {
      int y = __shfl_up(x, off);
      if (tid >= off) x += y;
    }
    int nb = bstart + x - v;            // exclusive prefix
    rowptr[b * 64 + tid] = nb;
    cur[tid] = nb;
  }
  __syncthreads();
  for (int i = bstart + tid; i < bend; i += 256) {
    unsigned u = pb[i];
    int pos = atomicAdd(&cur[(u >> 16) & 63], 1);
    ts[pos] = (unsigned short)(u & 0xffffu);
  }
}

// ---------------- upfront x1/w2 (all hops) + hop-0 h1 : thread-per-node ----------------
__global__ __launch_bounds__(256) void precompute_xw(
    const float* __restrict__ xA, const float* __restrict__ xP,
    const float* __restrict__ a1_ap, const float* __restrict__ a2_ap,
    const float* __restrict__ a1_aa, const float* __restrict__ a2_aa,
    const float* __restrict__ a1_pa, const float* __restrict__ a2_pa,
    const float* __restrict__ a1_pp, const float* __restrict__ a2_pp,
    float* __restrict__ x1all, float* __restrict__ w2all,
    float* __restrict__ h1_ap, float* __restrict__ h1_aa,
    float* __restrict__ h1_pa, float* __restrict__ h1_pp)
{
  int side = blockIdx.y;
  __shared__ float L[21 * DD];
  int tid = threadIdx.x;
  {
    const float* s0 = side ? a1_pa : a1_ap;
    const float* s1 = side ? a2_pa : a2_ap;
    const float* s2 = side ? a1_pp : a1_aa;
    const float* s3 = side ? a2_pp : a2_aa;
    const float* ex = side ? a2_ap : a2_pa;   // hop-0 cross-side extra
    for (int i = tid; i < 21 * DD; i += 256) {
      int k = i >> 6, d = i & 63;
      const float* src = (k < 5) ? s0 : (k < 10) ? s1 : (k < 15) ? s2 : (k < 20) ? s3 : ex;
      int hop = (k < 20) ? (k % 5) : 0;
      L[i] = src[hop * DD + d];
    }
  }
  __syncthreads();
  int j = blockIdx.x * 256 + tid;
  if (j >= NN) return;
  const float4* x4 = (const float4*)((side ? xP : xA) + (size_t)j * DD);
  float acc[21];
  #pragma unroll
  for (int k = 0; k < 21; ++k) acc[k] = 0.f;
  #pragma unroll
  for (int d0 = 0; d0 < 16; ++d0) {
    float4 v = x4[d0];
    #pragma unroll
    for (int c = 0; c < 4; ++c) {
      int d = d0 * 4 + c;
      float xv = (&v.x)[c];
      #pragma unroll
      for (int k = 0; k < 21; ++k) acc[k] = fmaf(xv, L[k * DD + d], acc[k]);
    }
  }
  int relA = side ? 2 : 0;
  #pragma unroll
  for (int i = 0; i < NHOP; ++i) {
    x1all[((size_t)(relA + 0) * NHOP + i) * NN + j] = acc[0 * 5 + i];
    w2all[((size_t)(relA + 0) * NHOP + i) * NN + j] =
        __expf(leaky02(acc[0 * 5 + i] + acc[1 * 5 + i]));
    x1all[((size_t)(relA + 1) * NHOP + i) * NN + j] = acc[2 * 5 + i];
    w2all[((size_t)(relA + 1) * NHOP + i) * NN + j] =
        __expf(leaky02(acc[2 * 5 + i] + acc[3 * 5 + i]));
  }
  if (side) { h1_pp[j] = acc[15]; h1_ap[j] = acc[20]; }
  else      { h1_aa[j] = acc[15]; h1_pa[j] = acc[20]; }
}

// ---------------- fused edge aggregation: 8-deep half2 gathers + XCD partition ----------------
struct AggRel {
  const float* x; const __half2* h2; const float* x1; const float* w2; const float* h1;
  const int* rowptr; const unsigned short* tsorted; float* out;
};

__global__ __launch_bounds__(256) void agg4_kernel(AggRel r0, AggRel r1, AggRel r2,
                                                   AggRel r3, int n)
{
  int bid = blockIdx.x;
  int g = (bid >> 2) & 1;
  int u = (bid >> 3) * 4 + (bid & 3);       // 0 .. n/2-1
  int half = n >> 2;                        // blocks per relation (10000)
  int relsel = u >= half;
  int nodeblk = relsel ? (u - half) : u;
  AggRel R;
  if (g == 0) R = relsel ? r2 : r1;
  else        R = relsel ? r3 : r0;

  int wid = nodeblk * 4 + (threadIdx.x >> 6);
  int lane = threadIdx.x & 63;
  int pair = lane >> 5;        // 0: even edges, 1: odd edges
  int c2 = lane & 31;          // half2 column index (cols 2*c2, 2*c2+1)

  int beg = R.rowptr[wid], end = R.rowptr[wid + 1];
  float x1i = R.x1[wid];
  float2 a0v = make_float2(0.f, 0.f), a1v = make_float2(0.f, 0.f);
  float2 a2v = make_float2(0.f, 0.f), a3v = make_float2(0.f, 0.f);
  float2 a4v = make_float2(0.f, 0.f), a5v = make_float2(0.f, 0.f);
  float2 a6v = make_float2(0.f, 0.f), a7v = make_float2(0.f, 0.f);
  float wsumL = 0.f;
  for (int c = beg; c < end; c += 64) {
    int idx = c + lane;
    int t = 0;
    float wv = 0.f;
    if (idx < end) {
      t = R.tsorted[idx];
      wv = __expf(leaky02(x1i + R.h1[t]));
    }
    wsumL += wv;
    int ne = min(64, end - c);
    for (int j = 0; j < ne; j += 16) {     // phantom edges: wv==0, t==0 (safe)
      int s0 = j + pair,      s1 = j + 2 + pair,  s2 = j + 4 + pair,  s3 = j + 6 + pair;
      int s4 = j + 8 + pair,  s5 = j + 10 + pair, s6 = j + 12 + pair, s7 = j + 14 + pair;
      int t0 = __shfl(t, s0), t1 = __shfl(t, s1), t2 = __shfl(t, s2), t3 = __shfl(t, s3);
      int t4 = __shfl(t, s4), t5 = __shfl(t, s5), t6 = __shfl(t, s6), t7 = __shfl(t, s7);
      float w0 = __shfl(wv, s0), w1 = __shfl(wv, s1), w2_ = __shfl(wv, s2), w3 = __shfl(wv, s3);
      float w4 = __shfl(wv, s4), w5 = __shfl(wv, s5), w6 = __shfl(wv, s6), w7 = __shfl(wv, s7);
      float2 f0 = __half22float2(R.h2[((unsigned)t0 << 5) + c2]);
      float2 f1 = __half22float2(R.h2[((unsigned)t1 << 5) + c2]);
      float2 f2 = __half22float2(R.h2[((unsigned)t2 << 5) + c2]);
      float2 f3 = __half22float2(R.h2[((unsigned)t3 << 5) + c2]);
      float2 f4 = __half22float2(R.h2[((unsigned)t4 << 5) + c2]);
      float2 f5 = __half22float2(R.h2[((unsigned)t5 << 5) + c2]);
      float2 f6 = __half22float2(R.h2[((unsigned)t6 << 5) + c2]);
      float2 f7 = __half22float2(R.h2[((unsigned)t7 << 5) + c2]);
      a0v.x = fmaf(w0, f0.x, a0v.x);  a0v.y = fmaf(w0, f0.y, a0v.y);
      a1v.x = fmaf(w1, f1.x, a1v.x);  a1v.y = fmaf(w1, f1.y, a1v.y);
      a2v.x = fmaf(w2_, f2.x, a2v.x); a2v.y = fmaf(w2_, f2.y, a2v.y);
      a3v.x = fmaf(w3, f3.x, a3v.x);  a3v.y = fmaf(w3, f3.y, a3v.y);
      a4v.x = fmaf(w4, f4.x, a4v.x);  a4v.y = fmaf(w4, f4.y, a4v.y);
      a5v.x = fmaf(w5, f5.x, a5v.x);  a5v.y = fmaf(w5, f5.y, a5v.y);
      a6v.x = fmaf(w6, f6.x, a6v.x);  a6v.y = fmaf(w6, f6.y, a6v.y);
      a7v.x = fmaf(w7, f7.x, a7v.x);  a7v.y = fmaf(w7, f7.y, a7v.y);
    }
  }
  float wsum = wred(wsumL);
  float2 acc;
  acc.x = ((a0v.x + a1v.x) + (a2v.x + a3v.x)) + ((a4v.x + a5v.x) + (a6v.x + a7v.x));
  acc.y = ((a0v.y + a1v.y) + (a2v.y + a3v.y)) + ((a4v.y + a5v.y) + (a6v.y + a7v.y));
  acc.x += __shfl_xor(acc.x, 32);            // fold odd-edge half into even half
  acc.y += __shfl_xor(acc.y, 32);
  if (pair == 0) {
    float w2v = R.w2[wid];
    float inv = 1.f / (wsum + w2v);
    float2 xv = ((const float2*)(R.x + (size_t)wid * DD))[c2];
    float2 o;
    o.x = fmaf(w2v, xv.x, acc.x) * inv;
    o.y = fmaf(w2v, xv.y, acc.y) * inv;
    ((float2*)(R.out + (size_t)wid * DD))[c2] = o;
  }
}

// ---------------- semantic attention partial sums (transposed z, float4 reads — R15) ----------------
__global__ __launch_bounds__(256) void sem_kernel(
    const float* __restrict__ eA0, const float* __restrict__ eA1,
    const float* __restrict__ eP0, const float* __restrict__ eP1,
    const float* __restrict__ Wa, const float* __restrict__ ba, const float* __restrict__ qa,
    const float* __restrict__ Wp, const float* __restrict__ bp, const float* __restrict__ qp,
    float* __restrict__ psums)
{
  int side = blockIdx.y;
  const float* e0 = side ? eP0 : eA0;
  const float* e1 = side ? eP1 : eA1;
  const float* W = side ? Wp : Wa;
  const float* b = side ? bp : ba;
  const float* q = side ? qp : qa;

  __shared__ float Ws[DD * NSEM];
  __shared__ float zt[2][DD][12];        // 8 nodes transposed (+4 pad, float4-aligned)
  __shared__ float red0[256], red1[256];
  int tid = threadIdx.x;
  {
    const float4* W4 = (const float4*)W;
    float4* Ws4 = (float4*)Ws;
    #pragma unroll
    for (int j = 0; j < 8; ++j) Ws4[tid + j * 256] = W4[tid + j * 256];
  }
  int slot = tid >> 7;                   // 2 slots x 4 nodes
  int k = tid & 127;
  float bk = b[k], qk = q[k];
  int base = blockIdx.x * 64;
  float sum0 = 0.f, sum1 = 0.f;
  for (int it = 0; it < 8; ++it) {
    #pragma unroll
    for (int j = 0; j < 4; ++j) {
      int idx = tid + j * 256;
      int d = idx & 63, m = (idx >> 6) & 1, nn = idx >> 7;
      zt[m][d][nn] = (m ? e1 : e0)[(size_t)(base + it * 8 + nn) * DD + d];
    }
    __syncthreads();
    float a0[4], a1[4];
    #pragma unroll
    for (int nn = 0; nn < 4; ++nn) { a0[nn] = bk; a1[nn] = bk; }
    #pragma unroll 8
    for (int d = 0; d < DD; ++d) {
      float w = Ws[d * NSEM + k];
      float4 za = *(const float4*)&zt[0][d][slot * 4];
      float4 zb = *(const float4*)&zt[1][d][slot * 4];
      a0[0] = fmaf(za.x, w, a0[0]);
      a0[1] = fmaf(za.y, w, a0[1]);
      a0[2] = fmaf(za.z, w, a0[2]);
      a0[3] = fmaf(za.w, w, a0[3]);
      a1[0] = fmaf(zb.x, w, a1[0]);
      a1[1] = fmaf(zb.y, w, a1[1]);
      a1[2] = fmaf(zb.z, w, a1[2]);
      a1[3] = fmaf(zb.w, w, a1[3]);
    }
    #pragma unroll
    for (int nn = 0; nn < 4; ++nn) {
      sum0 += tanh_fast(a0[nn]) * qk;
      sum1 += tanh_fast(a1[nn]) * qk;
    }
    __syncthreads();
  }
  red0[tid] = sum0;
  red1[tid] = sum1;
  __syncthreads();
  for (int off = 128; off; off >>= 1) {
    if (tid < off) { red0[tid] += red0[tid + off]; red1[tid] += red1[tid + off]; }
    __syncthreads();
  }
  if (tid == 0) {
    int idx = (side * gridDim.x + blockIdx.x) * 2;
    psums[idx + 0] = red0[0];
    psums[idx + 1] = red1[0];
  }
}

__global__ __launch_bounds__(256) void beta_kernel(const float* __restrict__ psums,
    float* __restrict__ beta, int nblk, float invn)
{
  __shared__ float s[4][256];
  int t = threadIdx.x;
  float a0 = 0.f, a1 = 0.f, p0 = 0.f, p1 = 0.f;
  for (int i = t; i < nblk; i += 256) {
    a0 += psums[i * 2];
    a1 += psums[i * 2 + 1];
    p0 += psums[(nblk + i) * 2];
    p1 += psums[(nblk + i) * 2 + 1];
  }
  s[0][t] = a0; s[1][t] = a1; s[2][t] = p0; s[3][t] = p1;
  __syncthreads();
  for (int off = 128; off; off >>= 1) {
    if (t < off) {
      s[0][t] += s[0][t + off]; s[1][t] += s[1][t + off];
      s[2][t] += s[2][t + off]; s[3][t] += s[3][t + off];
    }
    __syncthreads();
  }
  if (t == 0) {
    float m0 = s[0][0] * invn, m1 = s[1][0] * invn;
    float mx = fmaxf(m0, m1);
    float x0 = __expf(m0 - mx), x1 = __expf(m1 - mx);
    float inv = 1.f / (x0 + x1);
    beta[0] = x0 * inv; beta[1] = x1 * inv;
    m0 = s[2][0] * invn; m1 = s[3][0] * invn;
    mx = fmaxf(m0, m1);
    x0 = __expf(m0 - mx); x1 = __expf(m1 - mx);
    inv = 1.f / (x0 + x1);
    beta[2] = x0 * inv; beta[3] = x1 * inv;
  }
}

// ---------------- combine + ELU + fp16 copy + fused next-hop h1 (shfl 16-lane dots) ----------------
__global__ void combine2_kernel(const float4* __restrict__ eA0, const float4* __restrict__ eA1,
    const float4* __restrict__ eP0, const float4* __restrict__ eP1,
    const float* __restrict__ beta, float4* __restrict__ hA, float4* __restrict__ hP,
    __half2* __restrict__ hA16, __half2* __restrict__ hP16,
    const float* __restrict__ a2_ap_n, const float* __restrict__ a2_aa_n,
    const float* __restrict__ a2_pa_n, const float* __restrict__ a2_pp_n,
    float* __restrict__ h1_ap, float* __restrict__ h1_aa,
    float* __restrict__ h1_pa, float* __restrict__ h1_pp,
    int has_next, int nvec)
{
  int side = blockIdx.y;
  int i = blockIdx.x * 256 + threadIdx.x;
  if (i >= nvec) return;
  float b0 = beta[side * 2], b1 = beta[side * 2 + 1];
  float4 v0 = (side ? eP0 : eA0)[i];
  float4 v1 = (side ? eP1 : eA1)[i];
  float4 r;
  float t;
  t = b0 * v0.x + b1 * v1.x; r.x = t > 0.f ? t : (__expf(t) - 1.f);
  t = b0 * v0.y + b1 * v1.y; r.y = t > 0.f ? t : (__expf(t) - 1.f);
  t = b0 * v0.z + b1 * v1.z; r.z = t > 0.f ? t : (__expf(t) - 1.f);
  t = b0 * v0.w + b1 * v1.w; r.w = t > 0.f ? t : (__expf(t) - 1.f);
  (side ? hP : hA)[i] = r;
  (side ? hP16 : hA16)[i * 2 + 0] = __floats2half2_rn(r.x, r.y);
  (side ? hP16 : hA16)[i * 2 + 1] = __floats2half2_rn(r.z, r.w);
  if (has_next) {
    // row = i>>4; its 16 float4-threads are consecutive lanes in one wave
    int col4 = i & 15;
    const float* ax = side ? a2_ap_n : a2_aa_n;
    const float* ay = side ? a2_pp_n : a2_pa_n;
    float4 a4 = ((const float4*)ax)[col4];
    float4 c4 = ((const float4*)ay)[col4];
    float rx = r.x * a4.x + r.y * a4.y + r.z * a4.z + r.w * a4.w;
    float ry = r.x * c4.x + r.y * c4.y + r.z * c4.z + r.w * c4.w;
    #pragma unroll
    for (int m = 1; m < 16; m <<= 1) {
      rx += __shfl_xor(rx, m);
      ry += __shfl_xor(ry, m);
    }
    if ((threadIdx.x & 15) == 0) {
      int row = i >> 4;
      if (side) { h1_ap[row] = rx; h1_pp[row] = ry; }
      else      { h1_aa[row] = rx; h1_pa[row] = ry; }
    }
  }
}

// ---------------- final projection ----------------
__global__ void final_kernel(const float* __restrict__ hA, const float* __restrict__ W2,
    const float* __restrict__ b2, float* __restrict__ out, int n)
{
  int j = blockIdx.x * blockDim.x + threadIdx.x;
  if (j >= n) return;
  float acc0 = b2[0], acc1 = b2[1], acc2 = b2[2], acc3 = b2[3];
  const float4* hrow = (const float4*)(hA + (size_t)j * DD);
  #pragma unroll
  for (int d4 = 0; d4 < 16; ++d4) {
    float4 v = hrow[d4];
    #pragma unroll
    for (int c = 0; c < 4; ++c) {
      int d = d4 * 4 + c;
      float vv = (&v.x)[c];
      acc0 = fmaf(vv, W2[d * 4 + 0], acc0);
      acc1 = fmaf(vv, W2[d * 4 + 1], acc1);
      acc2 = fmaf(vv, W2[d * 4 + 2], acc2);
      acc3 = fmaf(vv, W2[d * 4 + 3], acc3);
    }
  }
  ((float4*)out)[j] = make_float4(acc0, acc1, acc2, acc3);
}

extern "C" void kernel_launch(void* const* d_in, const int* in_sizes, int n_in,
                              void* d_out, int out_size, void* d_ws, size_t ws_size,
                              hipStream_t stream)
{
  const float* x_author = (const float*)d_in[0];
  const float* x_paper  = (const float*)d_in[1];
  const float* W1_a = (const float*)d_in[2];
  const float* b1_a = (const float*)d_in[3];
  const float* W1_p = (const float*)d_in[4];
  const float* b1_p = (const float*)d_in[5];
  const float* a1_ap = (const float*)d_in[6];
  const float* a2_ap = (const float*)d_in[7];
  const float* a1_aa = (const float*)d_in[8];
  const float* a2_aa = (const float*)d_in[9];
  const float* a1_pa = (const float*)d_in[10];
  const float* a2_pa = (const float*)d_in[11];
  const float* a1_pp = (const float*)d_in[12];
  const float* a2_pp = (const float*)d_in[13];
  const float* semW_a = (const float*)d_in[14];
  const float* semb_a = (const float*)d_in[15];
  const float* semq_a = (const float*)d_in[16];
  const float* semW_p = (const float*)d_in[17];
  const float* semb_p = (const float*)d_in[18];
  const float* semq_p = (const float*)d_in[19];
  const float* W2 = (const float*)d_in[20];
  const float* b2 = (const float*)d_in[21];
  const int* ei[4] = {(const int*)d_in[22], (const int*)d_in[23],
                      (const int*)d_in[24], (const int*)d_in[25]};

  // ---- workspace carve ----
  char* w = (char*)d_ws;
  auto alloc = [&](size_t bytes) -> void* {
    void* p = (void*)w;
    w += (bytes + 255) & ~(size_t)255;
    return p;
  };
  const size_t matB = (size_t)NN * DD * sizeof(float);
  float* xA  = (float*)alloc(matB);
  float* xP  = (float*)alloc(matB);
  float* hA  = (float*)alloc(matB);
  float* hP  = (float*)alloc(matB);
  float* eA0 = (float*)alloc(matB);
  float* eA1 = (float*)alloc(matB);
  float* eP0 = (float*)alloc(matB);
  float* eP1 = (float*)alloc(matB);
  // fp16 gather buffers; hA16 aliases xA16 (proj rewrites each call before use)
  __half* xA16 = (__half*)alloc(matB / 2);
  __half* xP16 = (__half*)alloc(matB / 2);
  __half* hA16 = xA16;
  __half* hP16 = xP16;
  // pairbuf (4*E u32 = 12.8 MB) aliases eA0/eA1 (CSR build precedes e-buffer writes)
  unsigned* pairbuf = (unsigned*)eA0;
  int* rowptr[4]; unsigned short* tsorted[4];
  for (int r = 0; r < 4; ++r) {
    rowptr[r]  = (int*)alloc((NN + 1) * sizeof(int));
    tsorted[r] = (unsigned short*)alloc((size_t)EE * sizeof(unsigned short));
  }
  int* bcnt  = (int*)alloc((size_t)4 * NBK * sizeof(int));
  int* bbase = (int*)alloc((size_t)4 * (NBK + 1) * sizeof(int));
  int* bcur  = (int*)alloc((size_t)4 * NBK * sizeof(int));
  float* x1all = (float*)alloc((size_t)4 * NHOP * NN * sizeof(float));
  float* w2all = (float*)alloc((size_t)4 * NHOP * NN * sizeof(float));
  float* h1b[4];
  for (int r = 0; r < 4; ++r) h1b[r] = (float*)alloc(NN * sizeof(float));
  float* psums = (float*)alloc((size_t)2 * NBK * 2 * sizeof(float));
  float* betab = (float*)alloc(64);

  // ---- projections (both sides, one dispatch, BK=32) ----
  proj_gemm_relu2<<<dim3(NN / PBM, 2), 256, 0, stream>>>(
      x_author, W1_a, b1_a, xA, xA16,
      x_paper,  W1_p, b1_p, xP, xP16);

  // ---- CSR build (bucket-level counting; no per-node global histogram) ----
  const int NEB = (EE + BINCH - 1) / BINCH;
  zero_i32<<<(4 * NBK + 255) / 256, 256, 0, stream>>>(bcnt, 4 * NBK);
  binCount_kernel<<<dim3(NEB, 4), 256, 0, stream>>>(ei[0], ei[1], ei[2], ei[3], bcnt, EE);
  bucketScan_kernel<<<4, 1024, 0, stream>>>(bcnt, bbase, bcur,
      rowptr[0], rowptr[1], rowptr[2], rowptr[3], EE);
  binA_kernel<<<dim3(NEB, 4), 256, 0, stream>>>(
      ei[0], ei[1], ei[2], ei[3], bcur, pairbuf, EE);
  binB_kernel<<<dim3(NBK, 4), 256, 0, stream>>>(pairbuf, bbase,
      rowptr[0], rowptr[1], rowptr[2], rowptr[3],
      tsorted[0], tsorted[1], tsorted[2], tsorted[3], EE);

  // ---- upfront x1/w2 (all hops) + hop-0 h1 (thread-per-node) ----
  precompute_xw<<<dim3((NN + 255) / 256, 2), 256, 0, stream>>>(
      xA, xP, a1_ap, a2_ap, a1_aa, a2_aa, a1_pa, a2_pa, a1_pp, a2_pp,
      x1all, w2all, h1b[0], h1b[1], h1b[2], h1b[3]);

  // ---- hop loop ----
  const int CVEC = NN * DD / 4;
  for (int i = 0; i < NHOP; ++i) {
    #define X1(r) (x1all + ((size_t)(r) * NHOP + i) * NN)
    #define W2P(r) (w2all + ((size_t)(r) * NHOP + i) * NN)
    AggRel r0 = {xA, (const __half2*)hP16, X1(0), W2P(0), h1b[0], rowptr[0], tsorted[0], eA0};
    AggRel r1 = {xA, (const __half2*)hA16, X1(1), W2P(1), h1b[1], rowptr[1], tsorted[1], eA1};
    AggRel r2 = {xP, (const __half2*)hA16, X1(2), W2P(2), h1b[2], rowptr[2], tsorted[2], eP0};
    AggRel r3 = {xP, (const __half2*)hP16, X1(3), W2P(3), h1b[3], rowptr[3], tsorted[3], eP1};
    agg4_kernel<<<NN, 256, 0, stream>>>(r0, r1, r2, r3, NN);

    sem_kernel<<<dim3(NN / 64, 2), 256, 0, stream>>>(
        eA0, eA1, eP0, eP1,
        semW_a + (size_t)i * DD * NSEM, semb_a + i * NSEM, semq_a + i * NSEM,
        semW_p + (size_t)i * DD * NSEM, semb_p + i * NSEM, semq_p + i * NSEM,
        psums);
    beta_kernel<<<1, 256, 0, stream>>>(psums, betab, NN / 64, 1.f / NN);

    int inext = (i + 1 < NHOP) ? (i + 1) : i;
    combine2_kernel<<<dim3((CVEC + 255) / 256, 2), 256, 0, stream>>>(
        (const float4*)eA0, (const float4*)eA1, (const float4*)eP0, (const float4*)eP1,
        betab, (float4*)hA, (float4*)hP, (__half2*)hA16, (__half2*)hP16,
        a2_ap + inext * DD, a2_aa + inext * DD, a2_pa + inext * DD, a2_pp + inext * DD,
        h1b[0], h1b[1], h1b[2], h1b[3], (i + 1 < NHOP) ? 1 : 0, CVEC);
  }

  final_kernel<<<(NN + 255) / 256, 256, 0, stream>>>(hA, W2, b2, (float*)d_out, NN);
}

// Round 19
// 936.971 us; speedup vs baseline: 1.4647x; 1.0016x over previous
//
#include <hip/hip_runtime.h>
#include <hip/hip_fp16.h>

#define NN 40000
#define DD 64
#define EE 800000
#define NHOP 5
#define NSEM 128
#define NBK 625          // NN/64 buckets for binned scatter
#define BINCH 8192       // edges per binA/binCount block

__device__ __forceinline__ float leaky02(float v) { return v > 0.f ? v : 0.2f * v; }
__device__ __forceinline__ float tanh_fast(float x) {
  return 1.f - 2.f / (__expf(2.f * x) + 1.f);
}
__device__ __forceinline__ float wred(float x) {
  #pragma unroll
  for (int m = 1; m < 64; m <<= 1) x += __shfl_xor(x, m);
  return x;
}

// ---------------- zero kernel ----------------
__global__ void zero_i32(int* __restrict__ p, int n) {
  int i = blockIdx.x * blockDim.x + threadIdx.x;
  if (i < n) p[i] = 0;
}

// ---------------- projection GEMM: 64x64 tile, BK=32, 256 thr, 4x4 acc ----------------
// float2 As staging (pad 34 for 8B LDS alignment); sides interleaved in 1D grid.
#define PBM 64
#define PBK 32
__global__ __launch_bounds__(256) void proj_gemm_relu2(
    const float* __restrict__ Xa, const float* __restrict__ Wa,
    const float* __restrict__ ba, float* __restrict__ oa, __half* __restrict__ oa16,
    const float* __restrict__ Xp, const float* __restrict__ Wp,
    const float* __restrict__ bp, float* __restrict__ op, __half* __restrict__ op16)
{
  int side = blockIdx.x & 1;
  int bx = blockIdx.x >> 1;
  const float* X = side ? Xp : Xa;
  const float* W = side ? Wp : Wa;
  const float* bias = side ? bp : ba;
  float* out = side ? op : oa;
  __half* out16 = side ? op16 : oa16;
  int K = side ? 512 : 334;

  __shared__ float As[PBM][PBK + 2];
  __shared__ float Bs[PBK][DD];
  int tid = threadIdx.x;
  int tx = tid & 15;       // col quad (4 cols)
  int ty = tid >> 4;       // row quad (4 rows), 0..15
  int row0 = bx * PBM;
  float acc[4][4] = {{0.f}};
  int nk = (K + PBK - 1) / PBK;
  for (int kt = 0; kt < nk; ++kt) {
    int k0 = kt * PBK;
    // As: 64 rows x 16 float2 = 1024 float2, 4 per thread (K even -> pair guard = gk<K)
    #pragma unroll
    for (int j = 0; j < 4; ++j) {
      int idx = tid + j * 256;
      int r = idx >> 4, c2 = idx & 15;
      int gk = k0 + c2 * 2;
      float2 v = (gk < K) ? *(const float2*)(X + (size_t)(row0 + r) * K + gk)
                          : make_float2(0.f, 0.f);
      *(float2*)&As[r][c2 * 2] = v;
    }
    #pragma unroll
    for (int j = 0; j < 2; ++j) {
      int idx = tid + j * 256;
      int r = idx >> 4, c4 = idx & 15;
      int gk = k0 + r;
      float4 v = (gk < K) ? ((const float4*)(W + (size_t)gk * DD))[c4]
                          : make_float4(0.f, 0.f, 0.f, 0.f);
      ((float4*)&Bs[r][0])[c4] = v;
    }
    __syncthreads();
    #pragma unroll 8
    for (int kk = 0; kk < PBK; ++kk) {
      float a0 = As[ty * 4 + 0][kk];
      float a1 = As[ty * 4 + 1][kk];
      float a2 = As[ty * 4 + 2][kk];
      float a3 = As[ty * 4 + 3][kk];
      float4 bv = ((float4*)&Bs[kk][0])[tx];
      acc[0][0] = fmaf(a0, bv.x, acc[0][0]);
      acc[0][1] = fmaf(a0, bv.y, acc[0][1]);
      acc[0][2] = fmaf(a0, bv.z, acc[0][2]);
      acc[0][3] = fmaf(a0, bv.w, acc[0][3]);
      acc[1][0] = fmaf(a1, bv.x, acc[1][0]);
      acc[1][1] = fmaf(a1, bv.y, acc[1][1]);
      acc[1][2] = fmaf(a1, bv.z, acc[1][2]);
      acc[1][3] = fmaf(a1, bv.w, acc[1][3]);
      acc[2][0] = fmaf(a2, bv.x, acc[2][0]);
      acc[2][1] = fmaf(a2, bv.y, acc[2][1]);
      acc[2][2] = fmaf(a2, bv.z, acc[2][2]);
      acc[2][3] = fmaf(a2, bv.w, acc[2][3]);
      acc[3][0] = fmaf(a3, bv.x, acc[3][0]);
      acc[3][1] = fmaf(a3, bv.y, acc[3][1]);
      acc[3][2] = fmaf(a3, bv.z, acc[3][2]);
      acc[3][3] = fmaf(a3, bv.w, acc[3][3]);
    }
    __syncthreads();
  }
  float4 bb = ((const float4*)bias)[tx];
  #pragma unroll
  for (int i = 0; i < 4; ++i) {
    int gr = row0 + ty * 4 + i;
    float4 v;
    v.x = fmaxf(acc[i][0] + bb.x, 0.f);
    v.y = fmaxf(acc[i][1] + bb.y, 0.f);
    v.z = fmaxf(acc[i][2] + bb.z, 0.f);
    v.w = fmaxf(acc[i][3] + bb.w, 0.f);
    ((float4*)(out + (size_t)gr * DD))[tx] = v;
    __half2 p0 = __floats2half2_rn(v.x, v.y);
    __half2 p1 = __floats2half2_rn(v.z, v.w);
    ((__half2*)(out16 + (size_t)gr * DD))[tx * 2 + 0] = p0;
    ((__half2*)(out16 + (size_t)gr * DD))[tx * 2 + 1] = p1;
  }
}

// ---------------- CSR build: bucket counts (LDS-privatized) ----------------
__global__ __launch_bounds__(256) void binCount_kernel(
    const int* __restrict__ e0, const int* __restrict__ e1,
    const int* __restrict__ e2, const int* __restrict__ e3,
    int* __restrict__ bcnt, int e)
{
  int rel = blockIdx.y;
  const int* S = rel == 0 ? e0 : rel == 1 ? e1 : rel == 2 ? e2 : e3;
  __shared__ int cnt[NBK];
  int tid = threadIdx.x;
  for (int b = tid; b < NBK; b += 256) cnt[b] = 0;
  __syncthreads();
  int e0i = blockIdx.x * BINCH;
  int ne = min(BINCH, e - e0i);
  for (int i = tid; i < ne; i += 256) atomicAdd(&cnt[S[e0i + i] >> 6], 1);
  __syncthreads();
  for (int b = tid; b < NBK; b += 256)
    if (cnt[b]) atomicAdd(&bcnt[rel * NBK + b], cnt[b]);
}

// bucket scan -> bucket bases + cursor seed; also sets rowptr[NN]=E
__global__ __launch_bounds__(1024) void bucketScan_kernel(
    const int* __restrict__ bcnt, int* __restrict__ bbase, int* __restrict__ bcur,
    int* __restrict__ rp0, int* __restrict__ rp1, int* __restrict__ rp2,
    int* __restrict__ rp3, int e)
{
  int rel = blockIdx.x;
  __shared__ int sh[1024];
  int t = threadIdx.x;
  int v = (t < NBK) ? bcnt[rel * NBK + t] : 0;
  sh[t] = v;
  __syncthreads();
  for (int off = 1; off < 1024; off <<= 1) {
    int y = (t >= off) ? sh[t - off] : 0;
    __syncthreads();
    sh[t] += y;
    __syncthreads();
  }
  if (t < NBK) {
    int base = sh[t] - v;
    bbase[rel * (NBK + 1) + t] = base;
    bcur[rel * NBK + t] = base;
  }
  if (t == 0) {
    bbase[rel * (NBK + 1) + NBK] = e;
    (rel == 0 ? rp0 : rel == 1 ? rp1 : rel == 2 ? rp2 : rp3)[NN] = e;
  }
}

// pass A: bin edges into buckets, packed u32 = (s&63)<<16 | t
__global__ __launch_bounds__(256) void binA_kernel(
    const int* __restrict__ e0, const int* __restrict__ e1,
    const int* __restrict__ e2, const int* __restrict__ e3,
    int* __restrict__ bcur, unsigned* __restrict__ pairbuf, int e)
{
  int rel = blockIdx.y;
  const int* S = rel == 0 ? e0 : rel == 1 ? e1 : rel == 2 ? e2 : e3;
  const int* T = S + e;
  unsigned* pb = pairbuf + (size_t)rel * e;
  __shared__ int cnt[NBK], base[NBK], cnt2[NBK];
  int tid = threadIdx.x;
  for (int b = tid; b < NBK; b += 256) { cnt[b] = 0; cnt2[b] = 0; }
  __syncthreads();
  int e0i = blockIdx.x * BINCH;
  int ne = min(BINCH, e - e0i);
  for (int i = tid; i < ne; i += 256) atomicAdd(&cnt[S[e0i + i] >> 6], 1);
  __syncthreads();
  for (int b = tid; b < NBK; b += 256)
    base[b] = cnt[b] ? atomicAdd(&bcur[rel * NBK + b], cnt[b]) : 0;
  __syncthreads();
  for (int i = tid; i < ne; i += 256) {
    int s = S[e0i + i];
    int t = T[e0i + i];
    int b = s >> 6;
    int off = atomicAdd(&cnt2[b], 1);
    pb[base[b] + off] = ((unsigned)(s & 63) << 16) | (unsigned)t;
  }
}

// pass B: per bucket — local per-node counts, wave prefix -> rowptr, place targets (u16)
__global__ __launch_bounds__(256) void binB_kernel(
    const unsigned* __restrict__ pairbuf, const int* __restrict__ bbase,
    int* __restrict__ rp0, int* __restrict__ rp1, int* __restrict__ rp2,
    int* __restrict__ rp3,
    unsigned short* __restrict__ ts0, unsigned short* __restrict__ ts1,
    unsigned short* __restrict__ ts2, unsigned short* __restrict__ ts3, int e)
{
  int rel = blockIdx.y;
  int* rowptr = rel == 0 ? rp0 : rel == 1 ? rp1 : rel == 2 ? rp2 : rp3;
  unsigned short* ts = rel == 0 ? ts0 : rel == 1 ? ts1 : rel == 2 ? ts2 : ts3;
  const unsigned* pb = pairbuf + (size_t)rel * e;
  int b = blockIdx.x;
  int bstart = bbase[rel * (NBK + 1) + b];
  int bend   = bbase[rel * (NBK + 1) + b + 1];
  __shared__ int ncnt[64], cur[64];
  int tid = threadIdx.x;
  if (tid < 64) ncnt[tid] = 0;
  __syncthreads();
  for (int i = bstart + tid; i < bend; i += 256)
    atomicAdd(&ncnt[(pb[i] >> 16) & 63], 1);
  __syncthreads();
  if (tid < 64) {                       // wave 0: 64-wide inclusive scan
    int v = ncnt[tid];
    int x = v;
    #pragma unroll
    for (int off = 1; off < 64; off <<= 1) {
      int y = __shfl_up(x, off);
      if (tid >= off) x += y;
    }
    int nb = bstart + x - v;            // exclusive prefix
    rowptr[b * 64 + tid] = nb;
    cur[tid] = nb;
  }
  __syncthreads();
  for (int i = bstart + tid; i < bend; i += 256) {
    unsigned u = pb[i];
    int pos = atomicAdd(&cur[(u >> 16) & 63], 1);
    ts[pos] = (unsigned short)(u & 0xffffu);
  }
}

// ---------------- upfront x1/w2 (all hops) + hop-0 h1 : thread-per-node ----------------
__global__ __launch_bounds__(256) void precompute_xw(
    const float* __restrict__ xA, const float* __restrict__ xP,
    const float* __restrict__ a1_ap, const float* __restrict__ a2_ap,
    const float* __restrict__ a1_aa, const float* __restrict__ a2_aa,
    const float* __restrict__ a1_pa, const float* __restrict__ a2_pa,
    const float* __restrict__ a1_pp, const float* __restrict__ a2_pp,
    float* __restrict__ x1all, float* __restrict__ w2all,
    float* __restrict__ h1_ap, float* __restrict__ h1_aa,
    float* __restrict__ h1_pa, float* __restrict__ h1_pp)
{
  int side = blockIdx.y;
  __shared__ float L[21 * DD];
  int tid = threadIdx.x;
  {
    const float* s0 = side ? a1_pa : a1_ap;
    const float* s1 = side ? a2_pa : a2_ap;
    const float* s2 = side ? a1_pp : a1_aa;
    const float* s3 = side ? a2_pp : a2_aa;
    const float* ex = side ? a2_ap : a2_pa;   // hop-0 cross-side extra
    for (int i = tid; i < 21 * DD; i += 256) {
      int k = i >> 6, d = i & 63;
      const float* src = (k < 5) ? s0 : (k < 10) ? s1 : (k < 15) ? s2 : (k < 20) ? s3 : ex;
      int hop = (k < 20) ? (k % 5) : 0;
      L[i] = src[hop * DD + d];
    }
  }
  __syncthreads();
  int j = blockIdx.x * 256 + tid;
  if (j >= NN) return;
  const float4* x4 = (const float4*)((side ? xP : xA) + (size_t)j * DD);
  float acc[21];
  #pragma unroll
  for (int k = 0; k < 21; ++k) acc[k] = 0.f;
  #pragma unroll
  for (int d0 = 0; d0 < 16; ++d0) {
    float4 v = x4[d0];
    #pragma unroll
    for (int c = 0; c < 4; ++c) {
      int d = d0 * 4 + c;
      float xv = (&v.x)[c];
      #pragma unroll
      for (int k = 0; k < 21; ++k) acc[k] = fmaf(xv, L[k * DD + d], acc[k]);
    }
  }
  int relA = side ? 2 : 0;
  #pragma unroll
  for (int i = 0; i < NHOP; ++i) {
    x1all[((size_t)(relA + 0) * NHOP + i) * NN + j] = acc[0 * 5 + i];
    w2all[((size_t)(relA + 0) * NHOP + i) * NN + j] =
        __expf(leaky02(acc[0 * 5 + i] + acc[1 * 5 + i]));
    x1all[((size_t)(relA + 1) * NHOP + i) * NN + j] = acc[2 * 5 + i];
    w2all[((size_t)(relA + 1) * NHOP + i) * NN + j] =
        __expf(leaky02(acc[2 * 5 + i] + acc[3 * 5 + i]));
  }
  if (side) { h1_pp[j] = acc[15]; h1_ap[j] = acc[20]; }
  else      { h1_aa[j] = acc[15]; h1_pa[j] = acc[20]; }
}

// ---------------- fused edge aggregation: 8-deep half2 gathers + XCD partition ----------------
struct AggRel {
  const float* x; const __half2* h2; const float* x1; const float* w2; const float* h1;
  const int* rowptr; const unsigned short* tsorted; float* out;
};

__global__ __launch_bounds__(256) void agg4_kernel(AggRel r0, AggRel r1, AggRel r2,
                                                   AggRel r3, int n)
{
  int bid = blockIdx.x;
  int g = (bid >> 2) & 1;
  int u = (bid >> 3) * 4 + (bid & 3);       // 0 .. n/2-1
  int half = n >> 2;                        // blocks per relation (10000)
  int relsel = u >= half;
  int nodeblk = relsel ? (u - half) : u;
  AggRel R;
  if (g == 0) R = relsel ? r2 : r1;
  else        R = relsel ? r3 : r0;

  int wid = nodeblk * 4 + (threadIdx.x >> 6);
  int lane = threadIdx.x & 63;
  int pair = lane >> 5;        // 0: even edges, 1: odd edges
  int c2 = lane & 31;          // half2 column index (cols 2*c2, 2*c2+1)

  int beg = R.rowptr[wid], end = R.rowptr[wid + 1];
  float x1i = R.x1[wid];
  float2 a0v = make_float2(0.f, 0.f), a1v = make_float2(0.f, 0.f);
  float2 a2v = make_float2(0.f, 0.f), a3v = make_float2(0.f, 0.f);
  float2 a4v = make_float2(0.f, 0.f), a5v = make_float2(0.f, 0.f);
  float2 a6v = make_float2(0.f, 0.f), a7v = make_float2(0.f, 0.f);
  float wsumL = 0.f;
  for (int c = beg; c < end; c += 64) {
    int idx = c + lane;
    int t = 0;
    float wv = 0.f;
    if (idx < end) {
      t = R.tsorted[idx];
      wv = __expf(leaky02(x1i + R.h1[t]));
    }
    wsumL += wv;
    int ne = min(64, end - c);
    for (int j = 0; j < ne; j += 16) {     // phantom edges: wv==0, t==0 (safe)
      int s0 = j + pair,      s1 = j + 2 + pair,  s2 = j + 4 + pair,  s3 = j + 6 + pair;
      int s4 = j + 8 + pair,  s5 = j + 10 + pair, s6 = j + 12 + pair, s7 = j + 14 + pair;
      int t0 = __shfl(t, s0), t1 = __shfl(t, s1), t2 = __shfl(t, s2), t3 = __shfl(t, s3);
      int t4 = __shfl(t, s4), t5 = __shfl(t, s5), t6 = __shfl(t, s6), t7 = __shfl(t, s7);
      float w0 = __shfl(wv, s0), w1 = __shfl(wv, s1), w2_ = __shfl(wv, s2), w3 = __shfl(wv, s3);
      float w4 = __shfl(wv, s4), w5 = __shfl(wv, s5), w6 = __shfl(wv, s6), w7 = __shfl(wv, s7);
      float2 f0 = __half22float2(R.h2[((unsigned)t0 << 5) + c2]);
      float2 f1 = __half22float2(R.h2[((unsigned)t1 << 5) + c2]);
      float2 f2 = __half22float2(R.h2[((unsigned)t2 << 5) + c2]);
      float2 f3 = __half22float2(R.h2[((unsigned)t3 << 5) + c2]);
      float2 f4 = __half22float2(R.h2[((unsigned)t4 << 5) + c2]);
      float2 f5 = __half22float2(R.h2[((unsigned)t5 << 5) + c2]);
      float2 f6 = __half22float2(R.h2[((unsigned)t6 << 5) + c2]);
      float2 f7 = __half22float2(R.h2[((unsigned)t7 << 5) + c2]);
      a0v.x = fmaf(w0, f0.x, a0v.x);  a0v.y = fmaf(w0, f0.y, a0v.y);
      a1v.x = fmaf(w1, f1.x, a1v.x);  a1v.y = fmaf(w1, f1.y, a1v.y);
      a2v.x = fmaf(w2_, f2.x, a2v.x); a2v.y = fmaf(w2_, f2.y, a2v.y);
      a3v.x = fmaf(w3, f3.x, a3v.x);  a3v.y = fmaf(w3, f3.y, a3v.y);
      a4v.x = fmaf(w4, f4.x, a4v.x);  a4v.y = fmaf(w4, f4.y, a4v.y);
      a5v.x = fmaf(w5, f5.x, a5v.x);  a5v.y = fmaf(w5, f5.y, a5v.y);
      a6v.x = fmaf(w6, f6.x, a6v.x);  a6v.y = fmaf(w6, f6.y, a6v.y);
      a7v.x = fmaf(w7, f7.x, a7v.x);  a7v.y = fmaf(w7, f7.y, a7v.y);
    }
  }
  float wsum = wred(wsumL);
  float2 acc;
  acc.x = ((a0v.x + a1v.x) + (a2v.x + a3v.x)) + ((a4v.x + a5v.x) + (a6v.x + a7v.x));
  acc.y = ((a0v.y + a1v.y) + (a2v.y + a3v.y)) + ((a4v.y + a5v.y) + (a6v.y + a7v.y));
  acc.x += __shfl_xor(acc.x, 32);            // fold odd-edge half into even half
  acc.y += __shfl_xor(acc.y, 32);
  if (pair == 0) {
    float w2v = R.w2[wid];
    float inv = 1.f / (wsum + w2v);
    float2 xv = ((const float2*)(R.x + (size_t)wid * DD))[c2];
    float2 o;
    o.x = fmaf(w2v, xv.x, acc.x) * inv;
    o.y = fmaf(w2v, xv.y, acc.y) * inv;
    ((float2*)(R.out + (size_t)wid * DD))[c2] = o;
  }
}

// ---------------- semantic attention partial sums (transposed z, float4 reads) ----------------
__global__ __launch_bounds__(256) void sem_kernel(
    const float* __restrict__ eA0, const float* __restrict__ eA1,
    const float* __restrict__ eP0, const float* __restrict__ eP1,
    const float* __restrict__ Wa, const float* __restrict__ ba, const float* __restrict__ qa,
    const float* __restrict__ Wp, const float* __restrict__ bp, const float* __restrict__ qp,
    float* __restrict__ psums)
{
  int side = blockIdx.y;
  const float* e0 = side ? eP0 : eA0;
  const float* e1 = side ? eP1 : eA1;
  const float* W = side ? Wp : Wa;
  const float* b = side ? bp : ba;
  const float* q = side ? qp : qa;

  __shared__ float Ws[DD * NSEM];
  __shared__ float zt[2][DD][12];        // 8 nodes transposed (+4 pad, float4-aligned)
  __shared__ float red0[256], red1[256];
  int tid = threadIdx.x;
  {
    const float4* W4 = (const float4*)W;
    float4* Ws4 = (float4*)Ws;
    #pragma unroll
    for (int j = 0; j < 8; ++j) Ws4[tid + j * 256] = W4[tid + j * 256];
  }
  int slot = tid >> 7;                   // 2 slots x 4 nodes
  int k = tid & 127;
  float bk = b[k], qk = q[k];
  int base = blockIdx.x * 64;
  float sum0 = 0.f, sum1 = 0.f;
  for (int it = 0; it < 8; ++it) {
    #pragma unroll
    for (int j = 0; j < 4; ++j) {
      int idx = tid + j * 256;
      int d = idx & 63, m = (idx >> 6) & 1, nn = idx >> 7;
      zt[m][d][nn] = (m ? e1 : e0)[(size_t)(base + it * 8 + nn) * DD + d];
    }
    __syncthreads();
    float a0[4], a1[4];
    #pragma unroll
    for (int nn = 0; nn < 4; ++nn) { a0[nn] = bk; a1[nn] = bk; }
    #pragma unroll 8
    for (int d = 0; d < DD; ++d) {
      float w = Ws[d * NSEM + k];
      float4 za = *(const float4*)&zt[0][d][slot * 4];
      float4 zb = *(const float4*)&zt[1][d][slot * 4];
      a0[0] = fmaf(za.x, w, a0[0]);
      a0[1] = fmaf(za.y, w, a0[1]);
      a0[2] = fmaf(za.z, w, a0[2]);
      a0[3] = fmaf(za.w, w, a0[3]);
      a1[0] = fmaf(zb.x, w, a1[0]);
      a1[1] = fmaf(zb.y, w, a1[1]);
      a1[2] = fmaf(zb.z, w, a1[2]);
      a1[3] = fmaf(zb.w, w, a1[3]);
    }
    #pragma unroll
    for (int nn = 0; nn < 4; ++nn) {
      sum0 += tanh_fast(a0[nn]) * qk;
      sum1 += tanh_fast(a1[nn]) * qk;
    }
    __syncthreads();
  }
  red0[tid] = sum0;
  red1[tid] = sum1;
  __syncthreads();
  for (int off = 128; off; off >>= 1) {
    if (tid < off) { red0[tid] += red0[tid + off]; red1[tid] += red1[tid + off]; }
    __syncthreads();
  }
  if (tid == 0) {
    int idx = (side * gridDim.x + blockIdx.x) * 2;
    psums[idx + 0] = red0[0];
    psums[idx + 1] = red1[0];
  }
}

__global__ __launch_bounds__(256) void beta_kernel(const float* __restrict__ psums,
    float* __restrict__ beta, int nblk, float invn)
{
  __shared__ float s[4][256];
  int t = threadIdx.x;
  float a0 = 0.f, a1 = 0.f, p0 = 0.f, p1 = 0.f;
  for (int i = t; i < nblk; i += 256) {
    a0 += psums[i * 2];
    a1 += psums[i * 2 + 1];
    p0 += psums[(nblk + i) * 2];
    p1 += psums[(nblk + i) * 2 + 1];
  }
  s[0][t] = a0; s[1][t] = a1; s[2][t] = p0; s[3][t] = p1;
  __syncthreads();
  for (int off = 128; off; off >>= 1) {
    if (t < off) {
      s[0][t] += s[0][t + off]; s[1][t] += s[1][t + off];
      s[2][t] += s[2][t + off]; s[3][t] += s[3][t + off];
    }
    __syncthreads();
  }
  if (t == 0) {
    float m0 = s[0][0] * invn, m1 = s[1][0] * invn;
    float mx = fmaxf(m0, m1);
    float x0 = __expf(m0 - mx), x1 = __expf(m1 - mx);
    float inv = 1.f / (x0 + x1);
    beta[0] = x0 * inv; beta[1] = x1 * inv;
    m0 = s[2][0] * invn; m1 = s[3][0] * invn;
    mx = fmaxf(m0, m1);
    x0 = __expf(m0 - mx); x1 = __expf(m1 - mx);
    inv = 1.f / (x0 + x1);
    beta[2] = x0 * inv; beta[3] = x1 * inv;
  }
}

// ---------------- combine + ELU + fp16 copy + fused next-hop h1 (shfl 16-lane dots) ----------------
__global__ void combine2_kernel(const float4* __restrict__ eA0, const float4* __restrict__ eA1,
    const float4* __restrict__ eP0, const float4* __restrict__ eP1,
    const float* __restrict__ beta, float4* __restrict__ hA, float4* __restrict__ hP,
    __half2* __restrict__ hA16, __half2* __restrict__ hP16,
    const float* __restrict__ a2_ap_n, const float* __restrict__ a2_aa_n,
    const float* __restrict__ a2_pa_n, const float* __restrict__ a2_pp_n,
    float* __restrict__ h1_ap, float* __restrict__ h1_aa,
    float* __restrict__ h1_pa, float* __restrict__ h1_pp,
    int has_next, int nvec)
{
  int side = blockIdx.y;
  int i = blockIdx.x * 256 + threadIdx.x;
  if (i >= nvec) return;
  float b0 = beta[side * 2], b1 = beta[side * 2 + 1];
  float4 v0 = (side ? eP0 : eA0)[i];
  float4 v1 = (side ? eP1 : eA1)[i];
  float4 r;
  float t;
  t = b0 * v0.x + b1 * v1.x; r.x = t > 0.f ? t : (__expf(t) - 1.f);
  t = b0 * v0.y + b1 * v1.y; r.y = t > 0.f ? t : (__expf(t) - 1.f);
  t = b0 * v0.z + b1 * v1.z; r.z = t > 0.f ? t : (__expf(t) - 1.f);
  t = b0 * v0.w + b1 * v1.w; r.w = t > 0.f ? t : (__expf(t) - 1.f);
  (side ? hP : hA)[i] = r;
  (side ? hP16 : hA16)[i * 2 + 0] = __floats2half2_rn(r.x, r.y);
  (side ? hP16 : hA16)[i * 2 + 1] = __floats2half2_rn(r.z, r.w);
  if (has_next) {
    // row = i>>4; its 16 float4-threads are consecutive lanes in one wave
    int col4 = i & 15;
    const float* ax = side ? a2_ap_n : a2_aa_n;
    const float* ay = side ? a2_pp_n : a2_pa_n;
    float4 a4 = ((const float4*)ax)[col4];
    float4 c4 = ((const float4*)ay)[col4];
    float rx = r.x * a4.x + r.y * a4.y + r.z * a4.z + r.w * a4.w;
    float ry = r.x * c4.x + r.y * c4.y + r.z * c4.z + r.w * c4.w;
    #pragma unroll
    for (int m = 1; m < 16; m <<= 1) {
      rx += __shfl_xor(rx, m);
      ry += __shfl_xor(ry, m);
    }
    if ((threadIdx.x & 15) == 0) {
      int row = i >> 4;
      if (side) { h1_ap[row] = rx; h1_pp[row] = ry; }
      else      { h1_aa[row] = rx; h1_pa[row] = ry; }
    }
  }
}

// ---------------- final projection ----------------
__global__ void final_kernel(const float* __restrict__ hA, const float* __restrict__ W2,
    const float* __restrict__ b2, float* __restrict__ out, int n)
{
  int j = blockIdx.x * blockDim.x + threadIdx.x;
  if (j >= n) return;
  float acc0 = b2[0], acc1 = b2[1], acc2 = b2[2], acc3 = b2[3];
  const float4* hrow = (const float4*)(hA + (size_t)j * DD);
  #pragma unroll
  for (int d4 = 0; d4 < 16; ++d4) {
    float4 v = hrow[d4];
    #pragma unroll
    for (int c = 0; c < 4; ++c) {
      int d = d4 * 4 + c;
      float vv = (&v.x)[c];
      acc0 = fmaf(vv, W2[d * 4 + 0], acc0);
      acc1 = fmaf(vv, W2[d * 4 + 1], acc1);
      acc2 = fmaf(vv, W2[d * 4 + 2], acc2);
      acc3 = fmaf(vv, W2[d * 4 + 3], acc3);
    }
  }
  ((float4*)out)[j] = make_float4(acc0, acc1, acc2, acc3);
}

extern "C" void kernel_launch(void* const* d_in, const int* in_sizes, int n_in,
                              void* d_out, int out_size, void* d_ws, size_t ws_size,
                              hipStream_t stream)
{
  const float* x_author = (const float*)d_in[0];
  const float* x_paper  = (const float*)d_in[1];
  const float* W1_a = (const float*)d_in[2];
  const float* b1_a = (const float*)d_in[3];
  const float* W1_p = (const float*)d_in[4];
  const float* b1_p = (const float*)d_in[5];
  const float* a1_ap = (const float*)d_in[6];
  const float* a2_ap = (const float*)d_in[7];
  const float* a1_aa = (const float*)d_in[8];
  const float* a2_aa = (const float*)d_in[9];
  const float* a1_pa = (const float*)d_in[10];
  const float* a2_pa = (const float*)d_in[11];
  const float* a1_pp = (const float*)d_in[12];
  const float* a2_pp = (const float*)d_in[13];
  const float* semW_a = (const float*)d_in[14];
  const float* semb_a = (const float*)d_in[15];
  const float* semq_a = (const float*)d_in[16];
  const float* semW_p = (const float*)d_in[17];
  const float* semb_p = (const float*)d_in[18];
  const float* semq_p = (const float*)d_in[19];
  const float* W2 = (const float*)d_in[20];
  const float* b2 = (const float*)d_in[21];
  const int* ei[4] = {(const int*)d_in[22], (const int*)d_in[23],
                      (const int*)d_in[24], (const int*)d_in[25]};

  // ---- workspace carve ----
  char* w = (char*)d_ws;
  auto alloc = [&](size_t bytes) -> void* {
    void* p = (void*)w;
    w += (bytes + 255) & ~(size_t)255;
    return p;
  };
  const size_t matB = (size_t)NN * DD * sizeof(float);
  float* xA  = (float*)alloc(matB);
  float* xP  = (float*)alloc(matB);
  float* hA  = (float*)alloc(matB);
  float* hP  = (float*)alloc(matB);
  float* eA0 = (float*)alloc(matB);
  float* eA1 = (float*)alloc(matB);
  float* eP0 = (float*)alloc(matB);
  float* eP1 = (float*)alloc(matB);
  // fp16 gather buffers; hA16 aliases xA16 (proj rewrites each call before use)
  __half* xA16 = (__half*)alloc(matB / 2);
  __half* xP16 = (__half*)alloc(matB / 2);
  __half* hA16 = xA16;
  __half* hP16 = xP16;
  // pairbuf (4*E u32 = 12.8 MB) aliases eA0/eA1 (CSR build precedes e-buffer writes)
  unsigned* pairbuf = (unsigned*)eA0;
  int* rowptr[4]; unsigned short* tsorted[4];
  for (int r = 0; r < 4; ++r) {
    rowptr[r]  = (int*)alloc((NN + 1) * sizeof(int));
    tsorted[r] = (unsigned short*)alloc((size_t)EE * sizeof(unsigned short));
  }
  int* bcnt  = (int*)alloc((size_t)4 * NBK * sizeof(int));
  int* bbase = (int*)alloc((size_t)4 * (NBK + 1) * sizeof(int));
  int* bcur  = (int*)alloc((size_t)4 * NBK * sizeof(int));
  float* x1all = (float*)alloc((size_t)4 * NHOP * NN * sizeof(float));
  float* w2all = (float*)alloc((size_t)4 * NHOP * NN * sizeof(float));
  float* h1b[4];
  for (int r = 0; r < 4; ++r) h1b[r] = (float*)alloc(NN * sizeof(float));
  float* psums = (float*)alloc((size_t)2 * NBK * 2 * sizeof(float));
  float* betab = (float*)alloc(64);

  // ---- projections (both sides interleaved in one 1D dispatch) ----
  proj_gemm_relu2<<<(NN / PBM) * 2, 256, 0, stream>>>(
      x_author, W1_a, b1_a, xA, xA16,
      x_paper,  W1_p, b1_p, xP, xP16);

  // ---- CSR build (bucket-level counting; no per-node global histogram) ----
  const int NEB = (EE + BINCH - 1) / BINCH;
  zero_i32<<<(4 * NBK + 255) / 256, 256, 0, stream>>>(bcnt, 4 * NBK);
  binCount_kernel<<<dim3(NEB, 4), 256, 0, stream>>>(ei[0], ei[1], ei[2], ei[3], bcnt, EE);
  bucketScan_kernel<<<4, 1024, 0, stream>>>(bcnt, bbase, bcur,
      rowptr[0], rowptr[1], rowptr[2], rowptr[3], EE);
  binA_kernel<<<dim3(NEB, 4), 256, 0, stream>>>(
      ei[0], ei[1], ei[2], ei[3], bcur, pairbuf, EE);
  binB_kernel<<<dim3(NBK, 4), 256, 0, stream>>>(pairbuf, bbase,
      rowptr[0], rowptr[1], rowptr[2], rowptr[3],
      tsorted[0], tsorted[1], tsorted[2], tsorted[3], EE);

  // ---- upfront x1/w2 (all hops) + hop-0 h1 (thread-per-node) ----
  precompute_xw<<<dim3((NN + 255) / 256, 2), 256, 0, stream>>>(
      xA, xP, a1_ap, a2_ap, a1_aa, a2_aa, a1_pa, a2_pa, a1_pp, a2_pp,
      x1all, w2all, h1b[0], h1b[1], h1b[2], h1b[3]);

  // ---- hop loop ----
  const int CVEC = NN * DD / 4;
  for (int i = 0; i < NHOP; ++i) {
    #define X1(r) (x1all + ((size_t)(r) * NHOP + i) * NN)
    #define W2P(r) (w2all + ((size_t)(r) * NHOP + i) * NN)
    AggRel r0 = {xA, (const __half2*)hP16, X1(0), W2P(0), h1b[0], rowptr[0], tsorted[0], eA0};
    AggRel r1 = {xA, (const __half2*)hA16, X1(1), W2P(1), h1b[1], rowptr[1], tsorted[1], eA1};
    AggRel r2 = {xP, (const __half2*)hA16, X1(2), W2P(2), h1b[2], rowptr[2], tsorted[2], eP0};
    AggRel r3 = {xP, (const __half2*)hP16, X1(3), W2P(3), h1b[3], rowptr[3], tsorted[3], eP1};
    agg4_kernel<<<NN, 256, 0, stream>>>(r0, r1, r2, r3, NN);

    sem_kernel<<<dim3(NN / 64, 2), 256, 0, stream>>>(
        eA0, eA1, eP0, eP1,
        semW_a + (size_t)i * DD * NSEM, semb_a + i * NSEM, semq_a + i * NSEM,
        semW_p + (size_t)i * DD * NSEM, semb_p + i * NSEM, semq_p + i * NSEM,
        psums);
    beta_kernel<<<1, 256, 0, stream>>>(psums, betab, NN / 64, 1.f / NN);

    int inext = (i + 1 < NHOP) ? (i + 1) : i;
    combine2_kernel<<<dim3((CVEC + 255) / 256, 2), 256, 0, stream>>>(
        (const float4*)eA0, (const float4*)eA1, (const float4*)eP0, (const float4*)eP1,
        betab, (float4*)hA, (float4*)hP, (__half2*)hA16, (__half2*)hP16,
        a2_ap + inext * DD, a2_aa + inext * DD, a2_pa + inext * DD, a2_pp + inext * DD,
        h1b[0], h1b[1], h1b[2], h1b[3], (i + 1 < NHOP) ? 1 : 0, CVEC);
  }

  final_kernel<<<(NN + 255) / 256, 256, 0, stream>>>(hA, W2, b2, (float*)d_out, NN);
}